// Round 2
// baseline (3959.692 us; speedup 1.0000x reference)
//
#include <hip/hip_runtime.h>
#include <hip/hip_bf16.h>
#include <math.h>

// Problem constants (fixed by the reference)
#define D_MODEL   1024
#define NUM_HEADS 16
#define HEAD_DIM  64
#define BATCH     4
#define SEQ       2048
#define THETA     10000.0
#define M_TOTAL   (BATCH * SEQ)          // 8192 rows

typedef __attribute__((ext_vector_type(8))) short bf16x8;   // 8 bf16 = 4 VGPR
typedef __attribute__((ext_vector_type(4))) float f32x4;    // MFMA accumulator

// ---------------------------------------------------------------------------
// fp32 <-> bf16 split helpers (RNE). a = hi + lo with |a - hi - lo| <= 2^-18|a|
// ---------------------------------------------------------------------------
__device__ __forceinline__ unsigned short f32_to_bf16_rne(float f) {
    unsigned int u = __float_as_uint(f);
    u += 0x7FFFu + ((u >> 16) & 1u);
    return (unsigned short)(u >> 16);
}
__device__ __forceinline__ float bf16_to_f32(unsigned short h) {
    return __uint_as_float(((unsigned int)h) << 16);
}

// ---------------------------------------------------------------------------
// RoPE cos/sin table: [SEQ][32] each, double-precision angle generation.
// ---------------------------------------------------------------------------
__global__ void rope_table_kernel(const int* __restrict__ pos,
                                  float* __restrict__ cos_t,
                                  float* __restrict__ sin_t) {
    int idx = blockIdx.x * blockDim.x + threadIdx.x;   // s*32 + i
    if (idx >= SEQ * 32) return;
    int s = idx >> 5;
    int i = idx & 31;
    double inv = pow((double)THETA, -((double)(2 * i)) / (double)HEAD_DIM);
    double ang = (double)pos[s] * inv;
    cos_t[idx] = (float)cos(ang);
    sin_t[idx] = (float)sin(ang);
}

// ---------------------------------------------------------------------------
// Split fp32 array -> hi/lo bf16 arrays (same layout). One float4 per thread.
// ---------------------------------------------------------------------------
__global__ void split_kernel(const float* __restrict__ src,
                             unsigned short* __restrict__ hi,
                             unsigned short* __restrict__ lo,
                             int n4) {
    int i = blockIdx.x * blockDim.x + threadIdx.x;
    if (i >= n4) return;
    float4 f = ((const float4*)src)[i];
    float fv[4] = {f.x, f.y, f.z, f.w};
    unsigned int hw[2], lw[2];
    #pragma unroll
    for (int j = 0; j < 2; ++j) {
        unsigned short h0 = f32_to_bf16_rne(fv[2*j]);
        unsigned short h1 = f32_to_bf16_rne(fv[2*j+1]);
        unsigned short l0 = f32_to_bf16_rne(fv[2*j]   - bf16_to_f32(h0));
        unsigned short l1 = f32_to_bf16_rne(fv[2*j+1] - bf16_to_f32(h1));
        hw[j] = (unsigned int)h0 | ((unsigned int)h1 << 16);
        lw[j] = (unsigned int)l0 | ((unsigned int)l1 << 16);
    }
    ((uint2*)hi)[i] = make_uint2(hw[0], hw[1]);
    ((uint2*)lo)[i] = make_uint2(lw[0], lw[1]);
}

// ---------------------------------------------------------------------------
// Split-precision MFMA GEMM: C[m][n] = sum_k A[m][k] * W[n][k], fp32-grade via
//   Ahi*Bhi + Ahi*Blo + Alo*Bhi  (3x mfma_f32_16x16x32_bf16, fp32 accum).
// 128x128 tile, BK=32, 256 threads = 4 waves (2x2), 4x4 16x16 frags per wave.
// LDS rows padded to LDK=40 shorts (80 B) -> ~2-way read conflicts (free).
// MODE 0: N-space = 3*1024 (Q|K|V), fused RoPE epilogue, scatter [B][H][S][64].
// MODE 1: plain write to D0 [m][1024].
// ---------------------------------------------------------------------------
#define LDK 40

template<int MODE>
__global__ __launch_bounds__(256)
void mfma_split_gemm(const unsigned short* __restrict__ Ah_g,   // [8192][1024]
                     const unsigned short* __restrict__ Al_g,
                     const unsigned short* __restrict__ Wh_g,   // [.][1024][1024]
                     const unsigned short* __restrict__ Wl_g,
                     const float* __restrict__ cos_t,
                     const float* __restrict__ sin_t,
                     float* __restrict__ D0,
                     float* __restrict__ D1,
                     float* __restrict__ D2)
{
    __shared__ unsigned short sAh[128 * LDK];
    __shared__ unsigned short sAl[128 * LDK];
    __shared__ unsigned short sBh[128 * LDK];
    __shared__ unsigned short sBl[128 * LDK];

    const int tid  = threadIdx.x;
    const int lane = tid & 63;

    int proj = 0, nloc;
    if (MODE == 0) { proj = blockIdx.x >> 3; nloc = (blockIdx.x & 7) * 128; }
    else           { nloc = blockIdx.x * 128; }
    const int m0 = blockIdx.y * 128;

    const unsigned short* __restrict__ Wh = Wh_g + (size_t)proj * D_MODEL * D_MODEL;
    const unsigned short* __restrict__ Wl = Wl_g + (size_t)proj * D_MODEL * D_MODEL;

    // staging map: thread -> (row, 16-element half-row)
    const int srow = tid >> 1;
    const int sseg = (tid & 1) * 16;

    // wave -> 64x64 output quadrant
    const int wr = ((tid >> 6) >> 1) * 64;
    const int wc = ((tid >> 6) & 1) * 64;

    f32x4 acc[4][4];
    #pragma unroll
    for (int i = 0; i < 4; ++i)
        #pragma unroll
        for (int j = 0; j < 4; ++j) {
            acc[i][j][0] = 0.f; acc[i][j][1] = 0.f;
            acc[i][j][2] = 0.f; acc[i][j][3] = 0.f;
        }

    const size_t a_row = (size_t)(m0   + srow) * D_MODEL + sseg;
    const size_t b_row = (size_t)(nloc + srow) * D_MODEL + sseg;

    for (int kt = 0; kt < D_MODEL; kt += 32) {
        uint4 ah0 = *(const uint4*)&Ah_g[a_row + kt];
        uint4 ah1 = *(const uint4*)&Ah_g[a_row + kt + 8];
        uint4 al0 = *(const uint4*)&Al_g[a_row + kt];
        uint4 al1 = *(const uint4*)&Al_g[a_row + kt + 8];
        uint4 bh0 = *(const uint4*)&Wh[b_row + kt];
        uint4 bh1 = *(const uint4*)&Wh[b_row + kt + 8];
        uint4 bl0 = *(const uint4*)&Wl[b_row + kt];
        uint4 bl1 = *(const uint4*)&Wl[b_row + kt + 8];
        __syncthreads();   // previous iteration's frag reads done
        *(uint4*)&sAh[srow * LDK + sseg]     = ah0;
        *(uint4*)&sAh[srow * LDK + sseg + 8] = ah1;
        *(uint4*)&sAl[srow * LDK + sseg]     = al0;
        *(uint4*)&sAl[srow * LDK + sseg + 8] = al1;
        *(uint4*)&sBh[srow * LDK + sseg]     = bh0;
        *(uint4*)&sBh[srow * LDK + sseg + 8] = bh1;
        *(uint4*)&sBl[srow * LDK + sseg]     = bl0;
        *(uint4*)&sBl[srow * LDK + sseg + 8] = bl1;
        __syncthreads();

        // fragment loads: lane l holds row/col (l&15), k = (l>>4)*8 + j
        const int fr = lane & 15;
        const int ko = (lane >> 4) * 8;
        bf16x8 fah[4], fal[4], fbh[4], fbl[4];
        #pragma unroll
        for (int i = 0; i < 4; ++i) {
            fah[i] = *(const bf16x8*)&sAh[(wr + i*16 + fr) * LDK + ko];
            fal[i] = *(const bf16x8*)&sAl[(wr + i*16 + fr) * LDK + ko];
            fbh[i] = *(const bf16x8*)&sBh[(wc + i*16 + fr) * LDK + ko];
            fbl[i] = *(const bf16x8*)&sBl[(wc + i*16 + fr) * LDK + ko];
        }
        #pragma unroll
        for (int mi = 0; mi < 4; ++mi)
            #pragma unroll
            for (int ni = 0; ni < 4; ++ni) {
                acc[mi][ni] = __builtin_amdgcn_mfma_f32_16x16x32_bf16(fah[mi], fbh[ni], acc[mi][ni], 0, 0, 0);
                acc[mi][ni] = __builtin_amdgcn_mfma_f32_16x16x32_bf16(fah[mi], fbl[ni], acc[mi][ni], 0, 0, 0);
                acc[mi][ni] = __builtin_amdgcn_mfma_f32_16x16x32_bf16(fal[mi], fbh[ni], acc[mi][ni], 0, 0, 0);
            }
    }

    // Epilogue. C/D frag layout: col = lane&15, row = (lane>>4)*4 + reg.
    const int fcol  = lane & 15;
    const int frow0 = (lane >> 4) * 4;
    #pragma unroll
    for (int mi = 0; mi < 4; ++mi) {
        #pragma unroll
        for (int ni = 0; ni < 4; ++ni) {
            const int n = nloc + wc + ni * 16 + fcol;
            #pragma unroll
            for (int r = 0; r < 4; ++r) {
                const int m = m0 + wr + mi * 16 + frow0 + r;
                float v = acc[mi][ni][r];
                if (MODE == 1) {
                    D0[(size_t)m * D_MODEL + n] = v;
                } else {
                    // RoPE pair (n even, n odd) lives in lanes l, l^1
                    const float other = __shfl_xor(v, 1);
                    const int s = m & (SEQ - 1);
                    const int b = m >> 11;
                    const int h = n >> 6;
                    const int d = n & 63;
                    float res = v;
                    if (proj != 2) {
                        const float c  = cos_t[s * 32 + (d >> 1)];
                        const float sn = sin_t[s * 32 + (d >> 1)];
                        res = (d & 1) ? fmaf(other, sn, v * c)      // r2 = x1*sn + x2*c
                                      : fmaf(-other, sn, v * c);    // r1 = x1*c  - x2*sn
                    }
                    float* __restrict__ dst = (proj == 0) ? D0 : (proj == 1 ? D1 : D2);
                    dst[(((size_t)b * NUM_HEADS + h) * SEQ + s) * HEAD_DIM + d] = res;
                }
            }
        }
    }
}

// ---------------------------------------------------------------------------
// Causal flash attention, fp32. One wave per block, one q-row per thread,
// 64 q-rows per block. K/V staged in LDS as 16x64 tiles. Online softmax is
// entirely thread-local. Epilogue emits hi/lo bf16 split for the out-proj.
// ---------------------------------------------------------------------------
#define AT_BQ 64
#define AT_BK 16

__global__ __launch_bounds__(64)
void attn_kernel(const float* __restrict__ q_ws,   // [B*H][S][64]
                 const float* __restrict__ k_ws,
                 const float* __restrict__ v_ws,
                 unsigned short* __restrict__ attn_h,  // [B*S][1024] bf16 hi
                 unsigned short* __restrict__ attn_l)  // [B*S][1024] bf16 lo
{
    __shared__ float Ks[AT_BK][HEAD_DIM];
    __shared__ float Vs[AT_BK][HEAD_DIM];

    const int blk  = blockIdx.x;
    const int qt   = blk % (SEQ / AT_BQ);          // q-tile index
    const int bh   = blk / (SEQ / AT_BQ);          // 0..63
    const int h    = bh % NUM_HEADS;
    const int b    = bh / NUM_HEADS;
    const int t    = threadIdx.x;
    const int qrow = qt * AT_BQ + t;

    const float scale = 0.125f;                    // 1/sqrt(64)
    const float* __restrict__ qptr = q_ws + ((size_t)bh * SEQ + qrow) * HEAD_DIM;
    float4 q[16];
    #pragma unroll
    for (int i = 0; i < 16; ++i) {
        q[i] = *(const float4*)&qptr[i * 4];
        q[i].x *= scale; q[i].y *= scale; q[i].z *= scale; q[i].w *= scale;
    }

    float o[64];
    #pragma unroll
    for (int d = 0; d < 64; ++d) o[d] = 0.f;
    float mmax = -INFINITY, l = 0.f;

    const float* __restrict__ kbase = k_ws + (size_t)bh * SEQ * HEAD_DIM;
    const float* __restrict__ vbase = v_ws + (size_t)bh * SEQ * HEAD_DIM;
    const int kend = (qt + 1) * AT_BQ;             // rows beyond are fully masked

    const int sr = t >> 2;                         // staging row 0..15
    const int sc = (t & 3) * 16;                   // staging col 0,16,32,48

    for (int k0 = 0; k0 < kend; k0 += AT_BK) {
        __syncthreads();
        {
            const float* ksrc = kbase + (size_t)(k0 + sr) * HEAD_DIM + sc;
            const float* vsrc = vbase + (size_t)(k0 + sr) * HEAD_DIM + sc;
            #pragma unroll
            for (int c = 0; c < 16; c += 4) {
                *(float4*)&Ks[sr][sc + c] = *(const float4*)&ksrc[c];
                *(float4*)&Vs[sr][sc + c] = *(const float4*)&vsrc[c];
            }
        }
        __syncthreads();

        float p[AT_BK];
        float tmax = -INFINITY;
        #pragma unroll
        for (int j = 0; j < AT_BK; ++j) {
            float s = 0.f;
            #pragma unroll
            for (int i = 0; i < 16; ++i) {
                float4 kv = *(const float4*)&Ks[j][i * 4];
                s = fmaf(q[i].x, kv.x, s);
                s = fmaf(q[i].y, kv.y, s);
                s = fmaf(q[i].z, kv.z, s);
                s = fmaf(q[i].w, kv.w, s);
            }
            if (k0 + j > qrow) s = -INFINITY;      // causal mask
            p[j] = s;
            tmax = fmaxf(tmax, s);
        }

        const float mnew = fmaxf(mmax, tmax);
        if (mnew > mmax) {                          // rescale only when max moved
            const float corr = __expf(mmax - mnew); // exp(-inf)=0 on first tile
            l *= corr;
            #pragma unroll
            for (int d = 0; d < 64; ++d) o[d] *= corr;
            mmax = mnew;
        }

        float psum = 0.f;
        #pragma unroll
        for (int j = 0; j < AT_BK; ++j) {
            p[j] = __expf(p[j] - mmax);             // masked -> exp(-inf)=0
            psum += p[j];
        }
        l += psum;

        #pragma unroll
        for (int j = 0; j < AT_BK; ++j) {
            const float pj = p[j];
            #pragma unroll
            for (int i = 0; i < 16; ++i) {
                float4 vv = *(const float4*)&Vs[j][i * 4];
                o[i * 4 + 0] = fmaf(pj, vv.x, o[i * 4 + 0]);
                o[i * 4 + 1] = fmaf(pj, vv.y, o[i * 4 + 1]);
                o[i * 4 + 2] = fmaf(pj, vv.z, o[i * 4 + 2]);
                o[i * 4 + 3] = fmaf(pj, vv.w, o[i * 4 + 3]);
            }
        }
    }

    const float inv_l = 1.f / l;
    unsigned short* __restrict__ hp =
        attn_h + ((size_t)b * SEQ + qrow) * D_MODEL + h * HEAD_DIM;
    unsigned short* __restrict__ lp =
        attn_l + ((size_t)b * SEQ + qrow) * D_MODEL + h * HEAD_DIM;
    #pragma unroll
    for (int i = 0; i < 16; ++i) {
        float f0 = o[i*4+0] * inv_l;
        float f1 = o[i*4+1] * inv_l;
        float f2 = o[i*4+2] * inv_l;
        float f3 = o[i*4+3] * inv_l;
        unsigned short h0 = f32_to_bf16_rne(f0);
        unsigned short h1 = f32_to_bf16_rne(f1);
        unsigned short h2 = f32_to_bf16_rne(f2);
        unsigned short h3 = f32_to_bf16_rne(f3);
        unsigned short l0 = f32_to_bf16_rne(f0 - bf16_to_f32(h0));
        unsigned short l1 = f32_to_bf16_rne(f1 - bf16_to_f32(h1));
        unsigned short l2 = f32_to_bf16_rne(f2 - bf16_to_f32(h2));
        unsigned short l3 = f32_to_bf16_rne(f3 - bf16_to_f32(h3));
        *(uint2*)&hp[i*4] = make_uint2((unsigned)h0 | ((unsigned)h1 << 16),
                                       (unsigned)h2 | ((unsigned)h3 << 16));
        *(uint2*)&lp[i*4] = make_uint2((unsigned)l0 | ((unsigned)l1 << 16),
                                       (unsigned)l2 | ((unsigned)l3 << 16));
    }
}

// ---------------------------------------------------------------------------
extern "C" void kernel_launch(void* const* d_in, const int* in_sizes, int n_in,
                              void* d_out, int out_size, void* d_ws, size_t ws_size,
                              hipStream_t stream) {
    const float* wq  = (const float*)d_in[0];
    const float* wk  = (const float*)d_in[1];
    const float* wv  = (const float*)d_in[2];
    const float* wo  = (const float*)d_in[3];
    const float* x   = (const float*)d_in[4];
    const int*   pos = (const int*)d_in[5];   // jax default: int32
    float* out = (float*)d_out;

    // workspace carve-up (~145 MiB)
    char* ws = (char*)d_ws;
    float* q_ws = (float*)ws;                 ws += (size_t)33554432;
    float* k_ws = (float*)ws;                 ws += (size_t)33554432;
    float* v_ws = (float*)ws;                 ws += (size_t)33554432;
    unsigned short* xh = (unsigned short*)ws; ws += (size_t)16777216;
    unsigned short* xl = (unsigned short*)ws; ws += (size_t)16777216;
    unsigned short* wh = (unsigned short*)ws; ws += (size_t)8388608;
    unsigned short* wl = (unsigned short*)ws; ws += (size_t)8388608;
    float* cos_t = (float*)ws;                ws += (size_t)SEQ * 32 * 4;
    float* sin_t = (float*)ws;                ws += (size_t)SEQ * 32 * 4;
    // xh/xl are dead after the QKV GEMM -> reuse for attention hi/lo output
    unsigned short* attn_h = xh;
    unsigned short* attn_l = xl;

    rope_table_kernel<<<(SEQ * 32 + 255) / 256, 256, 0, stream>>>(pos, cos_t, sin_t);

    // pre-split inputs into hi/lo bf16
    split_kernel<<<(2097152 + 255) / 256, 256, 0, stream>>>(x, xh, xl, 2097152);
    split_kernel<<<(262144 + 255) / 256, 256, 0, stream>>>(wq, wh,           wl,           262144);
    split_kernel<<<(262144 + 255) / 256, 256, 0, stream>>>(wk, wh + 1048576, wl + 1048576, 262144);
    split_kernel<<<(262144 + 255) / 256, 256, 0, stream>>>(wv, wh + 2097152, wl + 2097152, 262144);
    split_kernel<<<(262144 + 255) / 256, 256, 0, stream>>>(wo, wh + 3145728, wl + 3145728, 262144);

    // QKV projection + RoPE (MFMA, split precision)
    mfma_split_gemm<0><<<dim3(24, 64), 256, 0, stream>>>(
        xh, xl, wh, wl, cos_t, sin_t, q_ws, k_ws, v_ws);

    // causal flash attention (fp32 VALU)
    attn_kernel<<<dim3(BATCH * NUM_HEADS * (SEQ / AT_BQ)), AT_BQ, 0, stream>>>(
        q_ws, k_ws, v_ws, attn_h, attn_l);

    // output projection (MFMA, split precision)
    mfma_split_gemm<1><<<dim3(8, 64), 256, 0, stream>>>(
        attn_h, attn_l, wh + 3145728, wl + 3145728, cos_t, sin_t, out, out, out);
}

// Round 3
// 702.559 us; speedup vs baseline: 5.6361x; 5.6361x over previous
//
#include <hip/hip_runtime.h>
#include <hip/hip_bf16.h>
#include <math.h>

// Problem constants (fixed by the reference)
#define D_MODEL   1024
#define NUM_HEADS 16
#define HEAD_DIM  64
#define BATCH     4
#define SEQ       2048
#define THETA     10000.0
#define M_TOTAL   (BATCH * SEQ)          // 8192 rows

typedef __attribute__((ext_vector_type(8))) short bf16x8;   // 8 bf16 = 4 VGPR
typedef __attribute__((ext_vector_type(4))) float f32x4;    // MFMA accumulator

// ---------------------------------------------------------------------------
// fp32 <-> bf16 split helpers (RNE). a = hi + lo with |a - hi - lo| <= 2^-18|a|
// ---------------------------------------------------------------------------
__device__ __forceinline__ unsigned short f32_to_bf16_rne(float f) {
    unsigned int u = __float_as_uint(f);
    u += 0x7FFFu + ((u >> 16) & 1u);
    return (unsigned short)(u >> 16);
}
__device__ __forceinline__ float bf16_to_f32(unsigned short h) {
    return __uint_as_float(((unsigned int)h) << 16);
}

// ---------------------------------------------------------------------------
// RoPE cos/sin table: [SEQ][32] each, double-precision angle generation.
// ---------------------------------------------------------------------------
__global__ void rope_table_kernel(const int* __restrict__ pos,
                                  float* __restrict__ cos_t,
                                  float* __restrict__ sin_t) {
    int idx = blockIdx.x * blockDim.x + threadIdx.x;   // s*32 + i
    if (idx >= SEQ * 32) return;
    int s = idx >> 5;
    int i = idx & 31;
    double inv = pow((double)THETA, -((double)(2 * i)) / (double)HEAD_DIM);
    double ang = (double)pos[s] * inv;
    cos_t[idx] = (float)cos(ang);
    sin_t[idx] = (float)sin(ang);
}

// ---------------------------------------------------------------------------
// Split fp32 array -> hi/lo bf16 arrays (same layout). One float4 per thread.
// ---------------------------------------------------------------------------
__global__ void split_kernel(const float* __restrict__ src,
                             unsigned short* __restrict__ hi,
                             unsigned short* __restrict__ lo,
                             int n4) {
    int i = blockIdx.x * blockDim.x + threadIdx.x;
    if (i >= n4) return;
    float4 f = ((const float4*)src)[i];
    float fv[4] = {f.x, f.y, f.z, f.w};
    unsigned int hw[2], lw[2];
    #pragma unroll
    for (int j = 0; j < 2; ++j) {
        unsigned short h0 = f32_to_bf16_rne(fv[2*j]);
        unsigned short h1 = f32_to_bf16_rne(fv[2*j+1]);
        unsigned short l0 = f32_to_bf16_rne(fv[2*j]   - bf16_to_f32(h0));
        unsigned short l1 = f32_to_bf16_rne(fv[2*j+1] - bf16_to_f32(h1));
        hw[j] = (unsigned int)h0 | ((unsigned int)h1 << 16);
        lw[j] = (unsigned int)l0 | ((unsigned int)l1 << 16);
    }
    ((uint2*)hi)[i] = make_uint2(hw[0], hw[1]);
    ((uint2*)lo)[i] = make_uint2(lw[0], lw[1]);
}

// ---------------------------------------------------------------------------
// Split-precision MFMA GEMM: C[m][n] = sum_k A[m][k] * W[n][k] via
//   Ahi*Bhi + Ahi*Blo + Alo*Bhi  (3x mfma_f32_16x16x32_bf16, fp32 accum).
// 128x128 tile, BK=32, 256 threads = 4 waves (2x2), 4x4 16x16 frags per wave.
// MODE 0: N-space = 3*1024 (Q|K|V). Epilogue: RoPE+scale Q, RoPE K, split all
//         to bf16 hi/lo; Q/K -> [bh][S][64], V -> TRANSPOSED [bh][64][S].
// MODE 1: plain fp32 write to Dout [m][1024].
// ---------------------------------------------------------------------------
#define LDK 40

template<int MODE>
__global__ __launch_bounds__(256)
void mfma_split_gemm(const unsigned short* __restrict__ Ah_g,   // [8192][1024]
                     const unsigned short* __restrict__ Al_g,
                     const unsigned short* __restrict__ Wh_g,   // [.][1024][1024]
                     const unsigned short* __restrict__ Wl_g,
                     const float* __restrict__ cos_t,
                     const float* __restrict__ sin_t,
                     unsigned short* __restrict__ Qh_g,
                     unsigned short* __restrict__ Ql_g,
                     unsigned short* __restrict__ Kh_g,
                     unsigned short* __restrict__ Kl_g,
                     unsigned short* __restrict__ Vh_g,
                     unsigned short* __restrict__ Vl_g,
                     float* __restrict__ Dout)
{
    __shared__ unsigned short sAh[128 * LDK];
    __shared__ unsigned short sAl[128 * LDK];
    __shared__ unsigned short sBh[128 * LDK];
    __shared__ unsigned short sBl[128 * LDK];

    const int tid  = threadIdx.x;
    const int lane = tid & 63;

    int proj = 0, nloc;
    if (MODE == 0) { proj = blockIdx.x >> 3; nloc = (blockIdx.x & 7) * 128; }
    else           { nloc = blockIdx.x * 128; }
    const int m0 = blockIdx.y * 128;

    const unsigned short* __restrict__ Wh = Wh_g + (size_t)proj * D_MODEL * D_MODEL;
    const unsigned short* __restrict__ Wl = Wl_g + (size_t)proj * D_MODEL * D_MODEL;

    const int srow = tid >> 1;
    const int sseg = (tid & 1) * 16;

    const int wr = ((tid >> 6) >> 1) * 64;
    const int wc = ((tid >> 6) & 1) * 64;

    f32x4 acc[4][4];
    #pragma unroll
    for (int i = 0; i < 4; ++i)
        #pragma unroll
        for (int j = 0; j < 4; ++j) {
            acc[i][j][0] = 0.f; acc[i][j][1] = 0.f;
            acc[i][j][2] = 0.f; acc[i][j][3] = 0.f;
        }

    const size_t a_row = (size_t)(m0   + srow) * D_MODEL + sseg;
    const size_t b_row = (size_t)(nloc + srow) * D_MODEL + sseg;

    for (int kt = 0; kt < D_MODEL; kt += 32) {
        uint4 ah0 = *(const uint4*)&Ah_g[a_row + kt];
        uint4 ah1 = *(const uint4*)&Ah_g[a_row + kt + 8];
        uint4 al0 = *(const uint4*)&Al_g[a_row + kt];
        uint4 al1 = *(const uint4*)&Al_g[a_row + kt + 8];
        uint4 bh0 = *(const uint4*)&Wh[b_row + kt];
        uint4 bh1 = *(const uint4*)&Wh[b_row + kt + 8];
        uint4 bl0 = *(const uint4*)&Wl[b_row + kt];
        uint4 bl1 = *(const uint4*)&Wl[b_row + kt + 8];
        __syncthreads();
        *(uint4*)&sAh[srow * LDK + sseg]     = ah0;
        *(uint4*)&sAh[srow * LDK + sseg + 8] = ah1;
        *(uint4*)&sAl[srow * LDK + sseg]     = al0;
        *(uint4*)&sAl[srow * LDK + sseg + 8] = al1;
        *(uint4*)&sBh[srow * LDK + sseg]     = bh0;
        *(uint4*)&sBh[srow * LDK + sseg + 8] = bh1;
        *(uint4*)&sBl[srow * LDK + sseg]     = bl0;
        *(uint4*)&sBl[srow * LDK + sseg + 8] = bl1;
        __syncthreads();

        const int fr = lane & 15;
        const int ko = (lane >> 4) * 8;
        bf16x8 fah[4], fal[4], fbh[4], fbl[4];
        #pragma unroll
        for (int i = 0; i < 4; ++i) {
            fah[i] = *(const bf16x8*)&sAh[(wr + i*16 + fr) * LDK + ko];
            fal[i] = *(const bf16x8*)&sAl[(wr + i*16 + fr) * LDK + ko];
            fbh[i] = *(const bf16x8*)&sBh[(wc + i*16 + fr) * LDK + ko];
            fbl[i] = *(const bf16x8*)&sBl[(wc + i*16 + fr) * LDK + ko];
        }
        #pragma unroll
        for (int mi = 0; mi < 4; ++mi)
            #pragma unroll
            for (int ni = 0; ni < 4; ++ni) {
                acc[mi][ni] = __builtin_amdgcn_mfma_f32_16x16x32_bf16(fah[mi], fbh[ni], acc[mi][ni], 0, 0, 0);
                acc[mi][ni] = __builtin_amdgcn_mfma_f32_16x16x32_bf16(fah[mi], fbl[ni], acc[mi][ni], 0, 0, 0);
                acc[mi][ni] = __builtin_amdgcn_mfma_f32_16x16x32_bf16(fal[mi], fbh[ni], acc[mi][ni], 0, 0, 0);
            }
    }

    // Epilogue. C/D frag layout: col = lane&15, row = (lane>>4)*4 + reg.
    const int fcol  = lane & 15;
    const int frow0 = (lane >> 4) * 4;
    #pragma unroll
    for (int mi = 0; mi < 4; ++mi) {
        const int m_base = m0 + wr + mi * 16 + frow0;
        #pragma unroll
        for (int ni = 0; ni < 4; ++ni) {
            const int n = nloc + wc + ni * 16 + fcol;
            if (MODE == 1) {
                #pragma unroll
                for (int r = 0; r < 4; ++r)
                    Dout[(size_t)(m_base + r) * D_MODEL + n] = acc[mi][ni][r];
            } else {
                const int h = n >> 6;
                const int d = n & 63;
                if (proj == 2) {
                    // V: transpose-store [bh][d][S]; 4 consecutive s -> uint2
                    unsigned short vh[4], vl[4];
                    #pragma unroll
                    for (int r = 0; r < 4; ++r) {
                        float v = acc[mi][ni][r];
                        vh[r] = f32_to_bf16_rne(v);
                        vl[r] = f32_to_bf16_rne(v - bf16_to_f32(vh[r]));
                    }
                    const int b = m_base >> 11;
                    const int s = m_base & (SEQ - 1);
                    const size_t addr =
                        ((size_t)(b * NUM_HEADS + h) * HEAD_DIM + d) * SEQ + s;
                    *(uint2*)&Vh_g[addr] = make_uint2(
                        (unsigned)vh[0] | ((unsigned)vh[1] << 16),
                        (unsigned)vh[2] | ((unsigned)vh[3] << 16));
                    *(uint2*)&Vl_g[addr] = make_uint2(
                        (unsigned)vl[0] | ((unsigned)vl[1] << 16),
                        (unsigned)vl[2] | ((unsigned)vl[3] << 16));
                } else {
                    #pragma unroll
                    for (int r = 0; r < 4; ++r) {
                        const int m = m_base + r;
                        const int b = m >> 11;
                        const int s = m & (SEQ - 1);
                        float v = acc[mi][ni][r];
                        const float other = __shfl_xor(v, 1);
                        const float c  = cos_t[s * 32 + (d >> 1)];
                        const float sn = sin_t[s * 32 + (d >> 1)];
                        float res = (d & 1) ? fmaf(other, sn, v * c)
                                            : fmaf(-other, sn, v * c);
                        if (proj == 0) res *= 0.125f;   // fold 1/sqrt(64) into Q
                        unsigned short hi = f32_to_bf16_rne(res);
                        unsigned short lo = f32_to_bf16_rne(res - bf16_to_f32(hi));
                        const size_t addr =
                            ((size_t)(b * NUM_HEADS + h) * SEQ + s) * HEAD_DIM + d;
                        if (proj == 0) { Qh_g[addr] = hi; Ql_g[addr] = lo; }
                        else           { Kh_g[addr] = hi; Kl_g[addr] = lo; }
                    }
                }
            }
        }
    }
}

// ---------------------------------------------------------------------------
// MFMA flash attention, split precision (fp32-grade).
// 4 waves/block, 64 q-rows/block (16 per wave, Q-frags in registers).
// Key tiles of 64 staged in LDS (K row-major, V transposed), pad 72 shorts.
// Softmax row-reduce via shfl_xor within 16-lane groups (C-layout rows).
// P transposed C->A layout via per-wave LDS round-trip (hi/lo split).
// ---------------------------------------------------------------------------
#define KPAD 72

__global__ __launch_bounds__(256)
void attn_mfma_kernel(const unsigned short* __restrict__ Qh_g,
                      const unsigned short* __restrict__ Ql_g,
                      const unsigned short* __restrict__ Kh_g,
                      const unsigned short* __restrict__ Kl_g,
                      const unsigned short* __restrict__ Vh_g,  // [bh][64][S]
                      const unsigned short* __restrict__ Vl_g,
                      unsigned short* __restrict__ attn_h,      // [B*S][1024]
                      unsigned short* __restrict__ attn_l)
{
    __shared__ unsigned short sKh[64 * KPAD];
    __shared__ unsigned short sKl[64 * KPAD];
    __shared__ unsigned short sVh[64 * KPAD];
    __shared__ unsigned short sVl[64 * KPAD];
    __shared__ unsigned short sPh[4][16 * KPAD];
    __shared__ unsigned short sPl[4][16 * KPAD];

    const int bid = blockIdx.x;
    // XCD swizzle: 2048 blocks = 8 XCDs x 256; keep each bh on one XCD.
    const int swz  = (bid & 7) * 256 + (bid >> 3);
    const int bh   = swz >> 5;        // 0..63
    const int qt   = swz & 31;        // q-tile 0..31
    const int tid  = threadIdx.x;
    const int lane = tid & 63;
    const int wv   = tid >> 6;        // wave 0..3
    const int fr   = lane & 15;
    const int fg   = lane >> 4;       // 0..3

    // Q fragments (A-layout); Qh/Ql already roped + scaled by 1/8.
    const size_t qbase =
        ((size_t)bh * SEQ + qt * 64 + wv * 16 + fr) * HEAD_DIM + fg * 8;
    bf16x8 qh[2], ql[2];
    qh[0] = *(const bf16x8*)&Qh_g[qbase];
    qh[1] = *(const bf16x8*)&Qh_g[qbase + 32];
    ql[0] = *(const bf16x8*)&Ql_g[qbase];
    ql[1] = *(const bf16x8*)&Ql_g[qbase + 32];

    f32x4 Oacc[4];
    #pragma unroll
    for (int nd = 0; nd < 4; ++nd) {
        Oacc[nd][0] = 0.f; Oacc[nd][1] = 0.f; Oacc[nd][2] = 0.f; Oacc[nd][3] = 0.f;
    }
    float m_r[4] = {-INFINITY, -INFINITY, -INFINITY, -INFINITY};
    float l_r[4] = {0.f, 0.f, 0.f, 0.f};

    // staging: wave wv owns one array
    const unsigned short* __restrict__ g_src =
        (wv == 0) ? Kh_g : (wv == 1) ? Kl_g : (wv == 2) ? Vh_g : Vl_g;
    unsigned short* __restrict__ s_dst =
        (wv == 0) ? sKh : (wv == 1) ? sKl : (wv == 2) ? sVh : sVl;
    const bool isV = (wv >= 2);

    unsigned short* __restrict__ ph = &sPh[wv][0];
    unsigned short* __restrict__ pl = &sPl[wv][0];

    for (int kt0 = 0; kt0 <= qt; ++kt0) {
        __syncthreads();      // previous tile's LDS reads complete
        #pragma unroll
        for (int j = 0; j < 8; ++j) {
            const int flat = j * 64 + lane;
            const int row = flat >> 3, seg = flat & 7;
            const size_t gaddr = isV
                ? ((size_t)(bh * HEAD_DIM + row) * SEQ + kt0 * 64 + seg * 8)
                : ((size_t)(bh * SEQ + kt0 * 64 + row) * HEAD_DIM + seg * 8);
            uint4 v = *(const uint4*)&g_src[gaddr];
            *(uint4*)&s_dst[row * KPAD + seg * 8] = v;
        }
        __syncthreads();

        // ---- QK^T (3-term split) ----
        f32x4 S[4];
        #pragma unroll
        for (int nd = 0; nd < 4; ++nd) {
            S[nd][0] = 0.f; S[nd][1] = 0.f; S[nd][2] = 0.f; S[nd][3] = 0.f;
        }
        #pragma unroll
        for (int nd = 0; nd < 4; ++nd) {
            #pragma unroll
            for (int kt = 0; kt < 2; ++kt) {
                const int off = (nd * 16 + fr) * KPAD + kt * 32 + fg * 8;
                bf16x8 kh = *(const bf16x8*)&sKh[off];
                bf16x8 kl = *(const bf16x8*)&sKl[off];
                S[nd] = __builtin_amdgcn_mfma_f32_16x16x32_bf16(qh[kt], kh, S[nd], 0, 0, 0);
                S[nd] = __builtin_amdgcn_mfma_f32_16x16x32_bf16(qh[kt], kl, S[nd], 0, 0, 0);
                S[nd] = __builtin_amdgcn_mfma_f32_16x16x32_bf16(ql[kt], kh, S[nd], 0, 0, 0);
            }
        }

        // causal mask (diagonal tile only; q-tile == key-tile)
        if (kt0 == qt) {
            #pragma unroll
            for (int nd = 0; nd < 4; ++nd) {
                const int key = nd * 16 + fr;
                #pragma unroll
                for (int r = 0; r < 4; ++r) {
                    const int q = wv * 16 + fg * 4 + r;
                    if (key > q) S[nd][r] = -INFINITY;
                }
            }
        }

        // ---- online softmax (row = fg*4 + r within wave's 16 rows) ----
        #pragma unroll
        for (int r = 0; r < 4; ++r) {
            float t = fmaxf(fmaxf(S[0][r], S[1][r]), fmaxf(S[2][r], S[3][r]));
            t = fmaxf(t, __shfl_xor(t, 1));
            t = fmaxf(t, __shfl_xor(t, 2));
            t = fmaxf(t, __shfl_xor(t, 4));
            t = fmaxf(t, __shfl_xor(t, 8));
            const float mnew = fmaxf(m_r[r], t);
            const float corr = __expf(m_r[r] - mnew);   // exp(-inf)=0 first tile
            m_r[r] = mnew;
            #pragma unroll
            for (int nd = 0; nd < 4; ++nd) S[nd][r] = __expf(S[nd][r] - mnew);
            float s = S[0][r] + S[1][r] + S[2][r] + S[3][r];
            s += __shfl_xor(s, 1);
            s += __shfl_xor(s, 2);
            s += __shfl_xor(s, 4);
            s += __shfl_xor(s, 8);
            l_r[r] = l_r[r] * corr + s;
            #pragma unroll
            for (int nd = 0; nd < 4; ++nd) Oacc[nd][r] *= corr;
        }

        // ---- P (C-layout) -> per-wave LDS tile (A-layout source), hi/lo ----
        #pragma unroll
        for (int nd = 0; nd < 4; ++nd)
            #pragma unroll
            for (int r = 0; r < 4; ++r) {
                const float p = S[nd][r];
                const unsigned short hi = f32_to_bf16_rne(p);
                const unsigned short lo = f32_to_bf16_rne(p - bf16_to_f32(hi));
                const int a = (fg * 4 + r) * KPAD + nd * 16 + fr;
                ph[a] = hi;
                pl[a] = lo;
            }
        asm volatile("s_waitcnt lgkmcnt(0)" ::: "memory");  // P writes visible
        __builtin_amdgcn_sched_barrier(0);                  // rule 18

        // ---- PV (3-term split) ----
        #pragma unroll
        for (int kt = 0; kt < 2; ++kt) {
            const int poff = fr * KPAD + kt * 32 + fg * 8;
            bf16x8 pa_h = *(const bf16x8*)&ph[poff];
            bf16x8 pa_l = *(const bf16x8*)&pl[poff];
            #pragma unroll
            for (int nd = 0; nd < 4; ++nd) {
                const int voff = (nd * 16 + fr) * KPAD + kt * 32 + fg * 8;
                bf16x8 vh = *(const bf16x8*)&sVh[voff];
                bf16x8 vl = *(const bf16x8*)&sVl[voff];
                Oacc[nd] = __builtin_amdgcn_mfma_f32_16x16x32_bf16(pa_h, vh, Oacc[nd], 0, 0, 0);
                Oacc[nd] = __builtin_amdgcn_mfma_f32_16x16x32_bf16(pa_h, vl, Oacc[nd], 0, 0, 0);
                Oacc[nd] = __builtin_amdgcn_mfma_f32_16x16x32_bf16(pa_l, vh, Oacc[nd], 0, 0, 0);
            }
        }
    }

    // ---- epilogue: normalize, split hi/lo, scatter to [b][s][h*64+d] ----
    const int b  = bh >> 4;
    const int hh = bh & 15;
    #pragma unroll
    for (int r = 0; r < 4; ++r) {
        const float inv = 1.0f / l_r[r];
        const int s = qt * 64 + wv * 16 + fg * 4 + r;
        #pragma unroll
        for (int nd = 0; nd < 4; ++nd) {
            const int d = nd * 16 + fr;
            const float v = Oacc[nd][r] * inv;
            const unsigned short hi = f32_to_bf16_rne(v);
            const unsigned short lo = f32_to_bf16_rne(v - bf16_to_f32(hi));
            const size_t addr =
                ((size_t)b * SEQ + s) * D_MODEL + hh * HEAD_DIM + d;
            attn_h[addr] = hi;
            attn_l[addr] = lo;
        }
    }
}

// ---------------------------------------------------------------------------
extern "C" void kernel_launch(void* const* d_in, const int* in_sizes, int n_in,
                              void* d_out, int out_size, void* d_ws, size_t ws_size,
                              hipStream_t stream) {
    const float* wq  = (const float*)d_in[0];
    const float* wk  = (const float*)d_in[1];
    const float* wv  = (const float*)d_in[2];
    const float* wo  = (const float*)d_in[3];
    const float* x   = (const float*)d_in[4];
    const int*   pos = (const int*)d_in[5];   // jax default: int32
    float* out = (float*)d_out;

    // workspace carve-up (~152 MiB)
    const size_t QKV_BYTES = (size_t)BATCH * NUM_HEADS * SEQ * HEAD_DIM * 2; // 16.78MB
    char* ws = (char*)d_ws;
    unsigned short* Qh  = (unsigned short*)ws; ws += QKV_BYTES;
    unsigned short* Ql  = (unsigned short*)ws; ws += QKV_BYTES;
    unsigned short* Kh  = (unsigned short*)ws; ws += QKV_BYTES;
    unsigned short* Kl  = (unsigned short*)ws; ws += QKV_BYTES;
    unsigned short* Vth = (unsigned short*)ws; ws += QKV_BYTES;
    unsigned short* Vtl = (unsigned short*)ws; ws += QKV_BYTES;
    unsigned short* xh  = (unsigned short*)ws; ws += QKV_BYTES;
    unsigned short* xl  = (unsigned short*)ws; ws += QKV_BYTES;
    unsigned short* wh  = (unsigned short*)ws; ws += (size_t)4 * 1024 * 1024 * 2;
    unsigned short* wl  = (unsigned short*)ws; ws += (size_t)4 * 1024 * 1024 * 2;
    float* cos_t = (float*)ws;                 ws += (size_t)SEQ * 32 * 4;
    float* sin_t = (float*)ws;                 ws += (size_t)SEQ * 32 * 4;
    // xh/xl dead after QKV GEMM -> reuse as attention output hi/lo
    unsigned short* attn_h = xh;
    unsigned short* attn_l = xl;

    rope_table_kernel<<<(SEQ * 32 + 255) / 256, 256, 0, stream>>>(pos, cos_t, sin_t);

    // pre-split inputs into hi/lo bf16
    split_kernel<<<(2097152 + 255) / 256, 256, 0, stream>>>(x, xh, xl, 2097152);
    split_kernel<<<(262144 + 255) / 256, 256, 0, stream>>>(wq, wh,           wl,           262144);
    split_kernel<<<(262144 + 255) / 256, 256, 0, stream>>>(wk, wh + 1048576, wl + 1048576, 262144);
    split_kernel<<<(262144 + 255) / 256, 256, 0, stream>>>(wv, wh + 2097152, wl + 2097152, 262144);
    split_kernel<<<(262144 + 255) / 256, 256, 0, stream>>>(wo, wh + 3145728, wl + 3145728, 262144);

    // QKV projection + RoPE + split + V-transpose (MFMA, split precision)
    mfma_split_gemm<0><<<dim3(24, 64), 256, 0, stream>>>(
        xh, xl, wh, wl, cos_t, sin_t, Qh, Ql, Kh, Kl, Vth, Vtl, nullptr);

    // causal flash attention (MFMA, split precision)
    attn_mfma_kernel<<<dim3(2048), 256, 0, stream>>>(
        Qh, Ql, Kh, Kl, Vth, Vtl, attn_h, attn_l);

    // output projection (MFMA, split precision)
    mfma_split_gemm<1><<<dim3(8, 64), 256, 0, stream>>>(
        attn_h, attn_l, wh + 3145728, wl + 3145728, cos_t, sin_t,
        nullptr, nullptr, nullptr, nullptr, nullptr, nullptr, out);
}

// Round 5
// 548.350 us; speedup vs baseline: 7.2211x; 1.2812x over previous
//
#include <hip/hip_runtime.h>
#include <hip/hip_bf16.h>
#include <math.h>

// Problem constants (fixed by the reference)
#define D_MODEL   1024
#define NUM_HEADS 16
#define HEAD_DIM  64
#define BATCH     4
#define SEQ       2048
#define THETA     10000.0
#define M_TOTAL   (BATCH * SEQ)          // 8192 rows

typedef __attribute__((ext_vector_type(8)))  short bf16x8;   // 8 bf16 = 4 VGPR
typedef __attribute__((ext_vector_type(4)))  float f32x4;
typedef __attribute__((ext_vector_type(16))) float f32x16;

// ---------------------------------------------------------------------------
// fp32 <-> bf16 split helpers (RNE). a = hi + lo with |a - hi - lo| <= 2^-18|a|
// ---------------------------------------------------------------------------
__device__ __forceinline__ unsigned short f32_to_bf16_rne(float f) {
    unsigned int u = __float_as_uint(f);
    u += 0x7FFFu + ((u >> 16) & 1u);
    return (unsigned short)(u >> 16);
}
__device__ __forceinline__ float bf16_to_f32(unsigned short h) {
    return __uint_as_float(((unsigned int)h) << 16);
}
// packed pair: lo half = bf16(a), hi half = bf16(b)
__device__ __forceinline__ unsigned int cvt_pk_bf16(float a, float b) {
    unsigned int r;
    asm volatile("v_cvt_pk_bf16_f32 %0, %1, %2" : "=v"(r) : "v"(a), "v"(b));
    return r;
}

// ---------------------------------------------------------------------------
// RoPE cos/sin table: [SEQ][32] each, double-precision angle generation.
// ---------------------------------------------------------------------------
__global__ void rope_table_kernel(const int* __restrict__ pos,
                                  float* __restrict__ cos_t,
                                  float* __restrict__ sin_t) {
    int idx = blockIdx.x * blockDim.x + threadIdx.x;   // s*32 + i
    if (idx >= SEQ * 32) return;
    int s = idx >> 5;
    int i = idx & 31;
    double inv = pow((double)THETA, -((double)(2 * i)) / (double)HEAD_DIM);
    double ang = (double)pos[s] * inv;
    cos_t[idx] = (float)cos(ang);
    sin_t[idx] = (float)sin(ang);
}

// ---------------------------------------------------------------------------
// Split fp32 array -> hi/lo bf16 arrays (same layout). One float4 per thread.
// ---------------------------------------------------------------------------
__global__ void split_kernel(const float* __restrict__ src,
                             unsigned short* __restrict__ hi,
                             unsigned short* __restrict__ lo,
                             int n4) {
    int i = blockIdx.x * blockDim.x + threadIdx.x;
    if (i >= n4) return;
    float4 f = ((const float4*)src)[i];
    float fv[4] = {f.x, f.y, f.z, f.w};
    unsigned int hw[2], lw[2];
    #pragma unroll
    for (int j = 0; j < 2; ++j) {
        unsigned short h0 = f32_to_bf16_rne(fv[2*j]);
        unsigned short h1 = f32_to_bf16_rne(fv[2*j+1]);
        unsigned short l0 = f32_to_bf16_rne(fv[2*j]   - bf16_to_f32(h0));
        unsigned short l1 = f32_to_bf16_rne(fv[2*j+1] - bf16_to_f32(h1));
        hw[j] = (unsigned int)h0 | ((unsigned int)h1 << 16);
        lw[j] = (unsigned int)l0 | ((unsigned int)l1 << 16);
    }
    ((uint2*)hi)[i] = make_uint2(hw[0], hw[1]);
    ((uint2*)lo)[i] = make_uint2(lw[0], lw[1]);
}

// ---------------------------------------------------------------------------
// Split-precision MFMA GEMM (validated R3): C[m][n] = sum_k A[m][k]*W[n][k] via
//   Ahi*Bhi + Ahi*Blo + Alo*Bhi  (3x mfma_f32_16x16x32_bf16, fp32 accum).
// MODE 0: N-space = 3*1024 (Q|K|V). Epilogue: RoPE+scale(1/8) Q, RoPE K, split
//         to bf16 hi/lo; Q/K -> [bh][S][64], V -> TRANSPOSED [bh][64][S].
// MODE 1: plain fp32 write to Dout [m][1024].
// ---------------------------------------------------------------------------
#define LDK 40

template<int MODE>
__global__ __launch_bounds__(256)
void mfma_split_gemm(const unsigned short* __restrict__ Ah_g,   // [8192][1024]
                     const unsigned short* __restrict__ Al_g,
                     const unsigned short* __restrict__ Wh_g,   // [.][1024][1024]
                     const unsigned short* __restrict__ Wl_g,
                     const float* __restrict__ cos_t,
                     const float* __restrict__ sin_t,
                     unsigned short* __restrict__ Qh_g,
                     unsigned short* __restrict__ Ql_g,
                     unsigned short* __restrict__ Kh_g,
                     unsigned short* __restrict__ Kl_g,
                     unsigned short* __restrict__ Vh_g,
                     unsigned short* __restrict__ Vl_g,
                     float* __restrict__ Dout)
{
    __shared__ unsigned short sAh[128 * LDK];
    __shared__ unsigned short sAl[128 * LDK];
    __shared__ unsigned short sBh[128 * LDK];
    __shared__ unsigned short sBl[128 * LDK];

    const int tid  = threadIdx.x;
    const int lane = tid & 63;

    int proj = 0, nloc;
    if (MODE == 0) { proj = blockIdx.x >> 3; nloc = (blockIdx.x & 7) * 128; }
    else           { nloc = blockIdx.x * 128; }
    const int m0 = blockIdx.y * 128;

    const unsigned short* __restrict__ Wh = Wh_g + (size_t)proj * D_MODEL * D_MODEL;
    const unsigned short* __restrict__ Wl = Wl_g + (size_t)proj * D_MODEL * D_MODEL;

    const int srow = tid >> 1;
    const int sseg = (tid & 1) * 16;

    const int wr = ((tid >> 6) >> 1) * 64;
    const int wc = ((tid >> 6) & 1) * 64;

    f32x4 acc[4][4];
    #pragma unroll
    for (int i = 0; i < 4; ++i)
        #pragma unroll
        for (int j = 0; j < 4; ++j) {
            acc[i][j][0] = 0.f; acc[i][j][1] = 0.f;
            acc[i][j][2] = 0.f; acc[i][j][3] = 0.f;
        }

    const size_t a_row = (size_t)(m0   + srow) * D_MODEL + sseg;
    const size_t b_row = (size_t)(nloc + srow) * D_MODEL + sseg;

    for (int kt = 0; kt < D_MODEL; kt += 32) {
        uint4 ah0 = *(const uint4*)&Ah_g[a_row + kt];
        uint4 ah1 = *(const uint4*)&Ah_g[a_row + kt + 8];
        uint4 al0 = *(const uint4*)&Al_g[a_row + kt];
        uint4 al1 = *(const uint4*)&Al_g[a_row + kt + 8];
        uint4 bh0 = *(const uint4*)&Wh[b_row + kt];
        uint4 bh1 = *(const uint4*)&Wh[b_row + kt + 8];
        uint4 bl0 = *(const uint4*)&Wl[b_row + kt];
        uint4 bl1 = *(const uint4*)&Wl[b_row + kt + 8];
        __syncthreads();
        *(uint4*)&sAh[srow * LDK + sseg]     = ah0;
        *(uint4*)&sAh[srow * LDK + sseg + 8] = ah1;
        *(uint4*)&sAl[srow * LDK + sseg]     = al0;
        *(uint4*)&sAl[srow * LDK + sseg + 8] = al1;
        *(uint4*)&sBh[srow * LDK + sseg]     = bh0;
        *(uint4*)&sBh[srow * LDK + sseg + 8] = bh1;
        *(uint4*)&sBl[srow * LDK + sseg]     = bl0;
        *(uint4*)&sBl[srow * LDK + sseg + 8] = bl1;
        __syncthreads();

        const int fr = lane & 15;
        const int ko = (lane >> 4) * 8;
        bf16x8 fah[4], fal[4], fbh[4], fbl[4];
        #pragma unroll
        for (int i = 0; i < 4; ++i) {
            fah[i] = *(const bf16x8*)&sAh[(wr + i*16 + fr) * LDK + ko];
            fal[i] = *(const bf16x8*)&sAl[(wr + i*16 + fr) * LDK + ko];
            fbh[i] = *(const bf16x8*)&sBh[(wc + i*16 + fr) * LDK + ko];
            fbl[i] = *(const bf16x8*)&sBl[(wc + i*16 + fr) * LDK + ko];
        }
        #pragma unroll
        for (int mi = 0; mi < 4; ++mi)
            #pragma unroll
            for (int ni = 0; ni < 4; ++ni) {
                acc[mi][ni] = __builtin_amdgcn_mfma_f32_16x16x32_bf16(fah[mi], fbh[ni], acc[mi][ni], 0, 0, 0);
                acc[mi][ni] = __builtin_amdgcn_mfma_f32_16x16x32_bf16(fah[mi], fbl[ni], acc[mi][ni], 0, 0, 0);
                acc[mi][ni] = __builtin_amdgcn_mfma_f32_16x16x32_bf16(fal[mi], fbh[ni], acc[mi][ni], 0, 0, 0);
            }
    }

    // Epilogue. C/D frag layout: col = lane&15, row = (lane>>4)*4 + reg.
    const int fcol  = lane & 15;
    const int frow0 = (lane >> 4) * 4;
    #pragma unroll
    for (int mi = 0; mi < 4; ++mi) {
        const int m_base = m0 + wr + mi * 16 + frow0;
        #pragma unroll
        for (int ni = 0; ni < 4; ++ni) {
            const int n = nloc + wc + ni * 16 + fcol;
            if (MODE == 1) {
                #pragma unroll
                for (int r = 0; r < 4; ++r)
                    Dout[(size_t)(m_base + r) * D_MODEL + n] = acc[mi][ni][r];
            } else {
                const int h = n >> 6;
                const int d = n & 63;
                if (proj == 2) {
                    unsigned short vh[4], vl[4];
                    #pragma unroll
                    for (int r = 0; r < 4; ++r) {
                        float v = acc[mi][ni][r];
                        vh[r] = f32_to_bf16_rne(v);
                        vl[r] = f32_to_bf16_rne(v - bf16_to_f32(vh[r]));
                    }
                    const int b = m_base >> 11;
                    const int s = m_base & (SEQ - 1);
                    const size_t addr =
                        ((size_t)(b * NUM_HEADS + h) * HEAD_DIM + d) * SEQ + s;
                    *(uint2*)&Vh_g[addr] = make_uint2(
                        (unsigned)vh[0] | ((unsigned)vh[1] << 16),
                        (unsigned)vh[2] | ((unsigned)vh[3] << 16));
                    *(uint2*)&Vl_g[addr] = make_uint2(
                        (unsigned)vl[0] | ((unsigned)vl[1] << 16),
                        (unsigned)vl[2] | ((unsigned)vl[3] << 16));
                } else {
                    #pragma unroll
                    for (int r = 0; r < 4; ++r) {
                        const int m = m_base + r;
                        const int b = m >> 11;
                        const int s = m & (SEQ - 1);
                        float v = acc[mi][ni][r];
                        const float other = __shfl_xor(v, 1);
                        const float c  = cos_t[s * 32 + (d >> 1)];
                        const float sn = sin_t[s * 32 + (d >> 1)];
                        float res = (d & 1) ? fmaf(other, sn, v * c)
                                            : fmaf(-other, sn, v * c);
                        if (proj == 0) res *= 0.125f;   // fold 1/sqrt(64) into Q
                        unsigned short hi = f32_to_bf16_rne(res);
                        unsigned short lo = f32_to_bf16_rne(res - bf16_to_f32(hi));
                        const size_t addr =
                            ((size_t)(b * NUM_HEADS + h) * SEQ + s) * HEAD_DIM + d;
                        if (proj == 0) { Qh_g[addr] = hi; Ql_g[addr] = lo; }
                        else           { Kh_g[addr] = hi; Kl_g[addr] = lo; }
                    }
                }
            }
        }
    }
}

// ---------------------------------------------------------------------------
// Flash attention v2: swapped-QK^T 32x32x16 MFMA, split precision.
// Block = 4 waves, 128 q-rows (32/wave). Key tiles of 32, K + V^T in LDS.
// S^T = mfma(K,Q): lane holds P[16 keys] for q = lane&31 -> softmax in-reg,
// P->A-frag via cvt_pk_bf16 + shfl_xor(32) (no LDS round-trip).
// Online softmax with defer-max (THR=8). O = mfma(P, V^T-frags).
// ---------------------------------------------------------------------------
#define KSTR 72   // sK row stride in shorts (32 keys x 64 d + pad)
#define VSTR 40   // sV row stride in shorts (64 d x 32 keys + pad)

__global__ __launch_bounds__(256)
void attn_mfma2_kernel(const unsigned short* __restrict__ Qh_g,  // [bh][S][64]
                       const unsigned short* __restrict__ Ql_g,
                       const unsigned short* __restrict__ Kh_g,  // [bh][S][64]
                       const unsigned short* __restrict__ Kl_g,
                       const unsigned short* __restrict__ Vh_g,  // [bh][64][S]
                       const unsigned short* __restrict__ Vl_g,
                       unsigned short* __restrict__ attn_h,      // [B*S][1024]
                       unsigned short* __restrict__ attn_l)
{
    __shared__ unsigned short sKh[32 * KSTR];
    __shared__ unsigned short sKl[32 * KSTR];
    __shared__ unsigned short sVh[64 * VSTR];
    __shared__ unsigned short sVl[64 * VSTR];

    // grid: 1024 = 64 bh x 16 qb. XCD-chunked, qb descending (big blocks first).
    const int bid = blockIdx.x;
    const int swz = (bid & 7) * 128 + (bid >> 3);
    const int bh  = swz >> 4;
    const int qb  = 15 - (swz & 15);

    const int tid   = threadIdx.x;
    const int lane  = tid & 63;
    const int wv    = tid >> 6;          // wave 0..3
    const int lq    = lane & 31;         // q within wave tile (S^T col)
    const int hi5   = lane >> 5;         // 0/1
    const bool lo32 = (hi5 == 0);

    const int q0   = qb * 128 + wv * 32;         // wave's first q row
    const int diag = qb * 4 + wv;                // wave's diagonal tile index
    const int nt   = (qb + 1) * 4;               // tiles this block stages

    // ---- Q B-frags (hi/lo), 4 k-steps of 16 d. Pre-roped, pre-scaled. ----
    const size_t qrow_base = ((size_t)bh * SEQ + q0 + lq) * HEAD_DIM;
    bf16x8 qfh[4], qfl[4];
    #pragma unroll
    for (int kt = 0; kt < 4; ++kt) {
        qfh[kt] = *(const bf16x8*)&Qh_g[qrow_base + kt * 16 + hi5 * 8];
        qfl[kt] = *(const bf16x8*)&Ql_g[qrow_base + kt * 16 + hi5 * 8];
    }

    f32x16 oacc0 = {0.f}, oacc1 = {0.f};
    #pragma unroll
    for (int r = 0; r < 16; ++r) { oacc0[r] = 0.f; oacc1[r] = 0.f; }
    float m_st = -INFINITY;   // running max for q = lq
    float l_st = 0.f;         // running denom for q = lq

    // ---- staging map (256 threads, one 32-key tile) ----
    const int skey = tid >> 3, sdseg = (tid & 7) * 8;       // K: [32 keys][64 d]
    const int svd  = tid >> 2, svseg = (tid & 3) * 8;       // V: [64 d][32 keys]
    const size_t kg_base = ((size_t)bh * SEQ) * HEAD_DIM + (size_t)skey * HEAD_DIM + sdseg;
    const size_t vg_base = ((size_t)bh * HEAD_DIM + svd) * SEQ + svseg;

    uint4 r_kh, r_kl, r_vh, r_vl;
    // prologue: tile 0
    r_kh = *(const uint4*)&Kh_g[kg_base];
    r_kl = *(const uint4*)&Kl_g[kg_base];
    r_vh = *(const uint4*)&Vh_g[vg_base];
    r_vl = *(const uint4*)&Vl_g[vg_base];
    *(uint4*)&sKh[skey * KSTR + sdseg] = r_kh;
    *(uint4*)&sKl[skey * KSTR + sdseg] = r_kl;
    *(uint4*)&sVh[svd * VSTR + svseg]  = r_vh;
    *(uint4*)&sVl[svd * VSTR + svseg]  = r_vl;
    __syncthreads();

    for (int t = 0; t < nt; ++t) {
        // issue next tile's loads early (hidden under compute)
        if (t + 1 < nt) {
            const size_t koff = (size_t)(t + 1) * 32 * HEAD_DIM;
            const size_t voff = (size_t)(t + 1) * 32;
            r_kh = *(const uint4*)&Kh_g[kg_base + koff];
            r_kl = *(const uint4*)&Kl_g[kg_base + koff];
            r_vh = *(const uint4*)&Vh_g[vg_base + voff];
            r_vl = *(const uint4*)&Vl_g[vg_base + voff];
        }

        if (t <= diag) {   // wave-uniform: skip fully-masked tiles
            // ---- QK^T: S^T[key][q] = sum_d K[key][d] Q[q][d] ----
            f32x16 S;
            #pragma unroll
            for (int r = 0; r < 16; ++r) S[r] = 0.f;
            #pragma unroll
            for (int kt = 0; kt < 4; ++kt) {
                const int ko = (lane & 31) * KSTR + kt * 16 + hi5 * 8;
                bf16x8 kh = *(const bf16x8*)&sKh[ko];
                bf16x8 kl = *(const bf16x8*)&sKl[ko];
                S = __builtin_amdgcn_mfma_f32_32x32x16_bf16(kh, qfh[kt], S, 0, 0, 0);
                S = __builtin_amdgcn_mfma_f32_32x32x16_bf16(kh, qfl[kt], S, 0, 0, 0);
                S = __builtin_amdgcn_mfma_f32_32x32x16_bf16(kl, qfh[kt], S, 0, 0, 0);
            }

            // causal mask on the diagonal tile: key_local > q_local -> -inf
            if (t == diag) {
                #pragma unroll
                for (int r = 0; r < 16; ++r) {
                    const int keyl = (r & 3) + 8 * (r >> 2) + 4 * hi5;
                    if (keyl > lq) S[r] = -INFINITY;
                }
            }

            // ---- online softmax (q = lq; row split across lane, lane^32) ----
            float pmax = S[0];
            #pragma unroll
            for (int r = 1; r < 16; ++r) pmax = fmaxf(pmax, S[r]);
            pmax = fmaxf(pmax, __shfl_xor(pmax, 32));

            if (__any(pmax > m_st + 8.0f)) {       // rescale path (rare)
                const float mnew = fmaxf(m_st, pmax);
                const float corr = __expf(m_st - mnew);   // 0 on first tile
                m_st = mnew;
                l_st *= corr;
                #pragma unroll
                for (int r = 0; r < 16; ++r) {
                    const int qrow = (r & 3) + 8 * (r >> 2) + 4 * hi5;
                    const float c_o = __shfl(corr, qrow);  // corr of that q-row
                    oacc0[r] *= c_o;
                    oacc1[r] *= c_o;
                }
            }

            float psum = 0.f;
            #pragma unroll
            for (int r = 0; r < 16; ++r) {
                S[r] = __expf(S[r] - m_st);
                psum += S[r];
            }
            psum += __shfl_xor(psum, 32);
            l_st += psum;

            // ---- P -> A-frags (hi/lo) via cvt_pk + shfl_xor(32) ----
            #pragma unroll
            for (int h = 0; h < 2; ++h) {          // 16-key halves
                const int r0 = h * 8;
                unsigned int Xh[4], Xl[4];
                #pragma unroll
                for (int c = 0; c < 4; ++c) {
                    const float p0 = S[r0 + 2*c], p1 = S[r0 + 2*c + 1];
                    Xh[c] = cvt_pk_bf16(p0, p1);
                    const float l0 = p0 - __uint_as_float(Xh[c] << 16);
                    const float l1 = p1 - __uint_as_float(Xh[c] & 0xFFFF0000u);
                    Xl[c] = cvt_pk_bf16(l0, l1);
                }
                unsigned int Yh[4], Yl[4];
                #pragma unroll
                for (int c = 0; c < 4; ++c) {
                    Yh[c] = (unsigned int)__shfl_xor((int)Xh[c], 32);
                    Yl[c] = (unsigned int)__shfl_xor((int)Xl[c], 32);
                }
                union { unsigned int u[4]; bf16x8 v; } pah, pal;
                pah.u[0] = lo32 ? Xh[0] : Yh[2];
                pah.u[1] = lo32 ? Xh[1] : Yh[3];
                pah.u[2] = lo32 ? Yh[0] : Xh[2];
                pah.u[3] = lo32 ? Yh[1] : Xh[3];
                pal.u[0] = lo32 ? Xl[0] : Yl[2];
                pal.u[1] = lo32 ? Xl[1] : Yl[3];
                pal.u[2] = lo32 ? Yl[0] : Xl[2];
                pal.u[3] = lo32 ? Yl[1] : Xl[3];

                // ---- PV: O[q][d] += P[q][keys] V[keys][d], d-blocks of 32 ----
                const int vo0 = (0 * 32 + (lane & 31)) * VSTR + h * 16 + hi5 * 8;
                const int vo1 = (1 * 32 + (lane & 31)) * VSTR + h * 16 + hi5 * 8;
                bf16x8 vh0 = *(const bf16x8*)&sVh[vo0];
                bf16x8 vl0 = *(const bf16x8*)&sVl[vo0];
                bf16x8 vh1 = *(const bf16x8*)&sVh[vo1];
                bf16x8 vl1 = *(const bf16x8*)&sVl[vo1];
                oacc0 = __builtin_amdgcn_mfma_f32_32x32x16_bf16(pah.v, vh0, oacc0, 0, 0, 0);
                oacc0 = __builtin_amdgcn_mfma_f32_32x32x16_bf16(pah.v, vl0, oacc0, 0, 0, 0);
                oacc0 = __builtin_amdgcn_mfma_f32_32x32x16_bf16(pal.v, vh0, oacc0, 0, 0, 0);
                oacc1 = __builtin_amdgcn_mfma_f32_32x32x16_bf16(pah.v, vh1, oacc1, 0, 0, 0);
                oacc1 = __builtin_amdgcn_mfma_f32_32x32x16_bf16(pah.v, vl1, oacc1, 0, 0, 0);
                oacc1 = __builtin_amdgcn_mfma_f32_32x32x16_bf16(pal.v, vh1, oacc1, 0, 0, 0);
            }
        }

        __syncthreads();                 // all waves done reading LDS
        if (t + 1 < nt) {
            *(uint4*)&sKh[skey * KSTR + sdseg] = r_kh;
            *(uint4*)&sKl[skey * KSTR + sdseg] = r_kl;
            *(uint4*)&sVh[svd * VSTR + svseg]  = r_vh;
            *(uint4*)&sVl[svd * VSTR + svseg]  = r_vl;
            __syncthreads();             // next tile ready
        }
    }

    // ---- epilogue: normalize, split hi/lo, store [b][s][h*64+d] ----
    const int b  = bh >> 4;
    const int hh = bh & 15;
    const float linv = 1.0f / l_st;      // for q = lq (both lane halves hold it)
    #pragma unroll
    for (int r = 0; r < 16; ++r) {
        const int qrow = (r & 3) + 8 * (r >> 2) + 4 * hi5;
        const float li = __shfl(linv, qrow);
        const int s = q0 + qrow;
        const size_t rowb = ((size_t)b * SEQ + s) * D_MODEL + hh * HEAD_DIM;
        const float v0 = oacc0[r] * li;
        const float v1 = oacc1[r] * li;
        const unsigned short h0 = f32_to_bf16_rne(v0);
        const unsigned short h1 = f32_to_bf16_rne(v1);
        attn_h[rowb + (lane & 31)]      = h0;
        attn_h[rowb + 32 + (lane & 31)] = h1;
        attn_l[rowb + (lane & 31)]      = f32_to_bf16_rne(v0 - bf16_to_f32(h0));
        attn_l[rowb + 32 + (lane & 31)] = f32_to_bf16_rne(v1 - bf16_to_f32(h1));
    }
}

// ---------------------------------------------------------------------------
extern "C" void kernel_launch(void* const* d_in, const int* in_sizes, int n_in,
                              void* d_out, int out_size, void* d_ws, size_t ws_size,
                              hipStream_t stream) {
    const float* wq  = (const float*)d_in[0];
    const float* wk  = (const float*)d_in[1];
    const float* wv  = (const float*)d_in[2];
    const float* wo  = (const float*)d_in[3];
    const float* x   = (const float*)d_in[4];
    const int*   pos = (const int*)d_in[5];   // jax default: int32
    float* out = (float*)d_out;

    // workspace carve-up (~152 MiB)
    const size_t QKV_BYTES = (size_t)BATCH * NUM_HEADS * SEQ * HEAD_DIM * 2; // 16.78MB
    char* ws = (char*)d_ws;
    unsigned short* Qh  = (unsigned short*)ws; ws += QKV_BYTES;
    unsigned short* Ql  = (unsigned short*)ws; ws += QKV_BYTES;
    unsigned short* Kh  = (unsigned short*)ws; ws += QKV_BYTES;
    unsigned short* Kl  = (unsigned short*)ws; ws += QKV_BYTES;
    unsigned short* Vth = (unsigned short*)ws; ws += QKV_BYTES;
    unsigned short* Vtl = (unsigned short*)ws; ws += QKV_BYTES;
    unsigned short* xh  = (unsigned short*)ws; ws += QKV_BYTES;
    unsigned short* xl  = (unsigned short*)ws; ws += QKV_BYTES;
    unsigned short* wh  = (unsigned short*)ws; ws += (size_t)4 * 1024 * 1024 * 2;
    unsigned short* wl  = (unsigned short*)ws; ws += (size_t)4 * 1024 * 1024 * 2;
    float* cos_t = (float*)ws;                 ws += (size_t)SEQ * 32 * 4;
    float* sin_t = (float*)ws;                 ws += (size_t)SEQ * 32 * 4;
    // xh/xl dead after QKV GEMM -> reuse as attention output hi/lo
    unsigned short* attn_h = xh;
    unsigned short* attn_l = xl;

    rope_table_kernel<<<(SEQ * 32 + 255) / 256, 256, 0, stream>>>(pos, cos_t, sin_t);

    // pre-split inputs into hi/lo bf16
    split_kernel<<<(2097152 + 255) / 256, 256, 0, stream>>>(x, xh, xl, 2097152);
    split_kernel<<<(262144 + 255) / 256, 256, 0, stream>>>(wq, wh,           wl,           262144);
    split_kernel<<<(262144 + 255) / 256, 256, 0, stream>>>(wk, wh + 1048576, wl + 1048576, 262144);
    split_kernel<<<(262144 + 255) / 256, 256, 0, stream>>>(wv, wh + 2097152, wl + 2097152, 262144);
    split_kernel<<<(262144 + 255) / 256, 256, 0, stream>>>(wo, wh + 3145728, wl + 3145728, 262144);

    // QKV projection + RoPE + split + V-transpose (MFMA, split precision)
    mfma_split_gemm<0><<<dim3(24, 64), 256, 0, stream>>>(
        xh, xl, wh, wl, cos_t, sin_t, Qh, Ql, Kh, Kl, Vth, Vtl, nullptr);

    // causal flash attention v2 (swapped-QK 32x32 MFMA, split precision)
    attn_mfma2_kernel<<<dim3(1024), 256, 0, stream>>>(
        Qh, Ql, Kh, Kl, Vth, Vtl, attn_h, attn_l);

    // output projection (MFMA, split precision)
    mfma_split_gemm<1><<<dim3(8, 64), 256, 0, stream>>>(
        attn_h, attn_l, wh + 3145728, wl + 3145728, cos_t, sin_t,
        nullptr, nullptr, nullptr, nullptr, nullptr, nullptr, out);
}

// Round 6
// 501.320 us; speedup vs baseline: 7.8985x; 1.0938x over previous
//
#include <hip/hip_runtime.h>
#include <hip/hip_bf16.h>
#include <math.h>

// Problem constants (fixed by the reference)
#define D_MODEL   1024
#define NUM_HEADS 16
#define HEAD_DIM  64
#define BATCH     4
#define SEQ       2048
#define THETA     10000.0
#define M_TOTAL   (BATCH * SEQ)          // 8192 rows

typedef __attribute__((ext_vector_type(8)))  short bf16x8;   // 8 bf16 = 4 VGPR
typedef __attribute__((ext_vector_type(4)))  float f32x4;
typedef __attribute__((ext_vector_type(16))) float f32x16;

// ---------------------------------------------------------------------------
// fp32 <-> bf16 split helpers (RNE). a = hi + lo with |a - hi - lo| <= 2^-18|a|
// ---------------------------------------------------------------------------
__device__ __forceinline__ unsigned short f32_to_bf16_rne(float f) {
    unsigned int u = __float_as_uint(f);
    u += 0x7FFFu + ((u >> 16) & 1u);
    return (unsigned short)(u >> 16);
}
__device__ __forceinline__ float bf16_to_f32(unsigned short h) {
    return __uint_as_float(((unsigned int)h) << 16);
}
// packed pair: lo half = bf16(a), hi half = bf16(b)
__device__ __forceinline__ unsigned int cvt_pk_bf16(float a, float b) {
    unsigned int r;
    asm volatile("v_cvt_pk_bf16_f32 %0, %1, %2" : "=v"(r) : "v"(a), "v"(b));
    return r;
}

// ---------------------------------------------------------------------------
// RoPE cos/sin table: [SEQ][32] each, double-precision angle generation.
// ---------------------------------------------------------------------------
__global__ void rope_table_kernel(const int* __restrict__ pos,
                                  float* __restrict__ cos_t,
                                  float* __restrict__ sin_t) {
    int idx = blockIdx.x * blockDim.x + threadIdx.x;   // s*32 + i
    if (idx >= SEQ * 32) return;
    int s = idx >> 5;
    int i = idx & 31;
    double inv = pow((double)THETA, -((double)(2 * i)) / (double)HEAD_DIM);
    double ang = (double)pos[s] * inv;
    cos_t[idx] = (float)cos(ang);
    sin_t[idx] = (float)sin(ang);
}

// ---------------------------------------------------------------------------
// Split fp32 array -> hi/lo bf16 arrays (same layout). One float4 per thread.
// ---------------------------------------------------------------------------
__global__ void split_kernel(const float* __restrict__ src,
                             unsigned short* __restrict__ hi,
                             unsigned short* __restrict__ lo,
                             int n4) {
    int i = blockIdx.x * blockDim.x + threadIdx.x;
    if (i >= n4) return;
    float4 f = ((const float4*)src)[i];
    float fv[4] = {f.x, f.y, f.z, f.w};
    unsigned int hw[2], lw[2];
    #pragma unroll
    for (int j = 0; j < 2; ++j) {
        unsigned short h0 = f32_to_bf16_rne(fv[2*j]);
        unsigned short h1 = f32_to_bf16_rne(fv[2*j+1]);
        unsigned short l0 = f32_to_bf16_rne(fv[2*j]   - bf16_to_f32(h0));
        unsigned short l1 = f32_to_bf16_rne(fv[2*j+1] - bf16_to_f32(h1));
        hw[j] = (unsigned int)h0 | ((unsigned int)h1 << 16);
        lw[j] = (unsigned int)l0 | ((unsigned int)l1 << 16);
    }
    ((uint2*)hi)[i] = make_uint2(hw[0], hw[1]);
    ((uint2*)lo)[i] = make_uint2(lw[0], lw[1]);
}

// ---------------------------------------------------------------------------
// Split-precision MFMA GEMM (validated R3): C[m][n] = sum_k A[m][k]*W[n][k] via
//   Ahi*Bhi + Ahi*Blo + Alo*Bhi  (3x mfma_f32_16x16x32_bf16, fp32 accum).
// MODE 0: N-space = 3*1024 (Q|K|V). Epilogue: RoPE+scale(1/8) Q, RoPE K, split
//         to bf16 hi/lo; Q/K -> [bh][S][64], V -> TRANSPOSED [bh][64][S].
// MODE 1: plain fp32 write to Dout [m][1024].
// ---------------------------------------------------------------------------
#define LDK 40

template<int MODE>
__global__ __launch_bounds__(256)
void mfma_split_gemm(const unsigned short* __restrict__ Ah_g,   // [8192][1024]
                     const unsigned short* __restrict__ Al_g,
                     const unsigned short* __restrict__ Wh_g,   // [.][1024][1024]
                     const unsigned short* __restrict__ Wl_g,
                     const float* __restrict__ cos_t,
                     const float* __restrict__ sin_t,
                     unsigned short* __restrict__ Qh_g,
                     unsigned short* __restrict__ Ql_g,
                     unsigned short* __restrict__ Kh_g,
                     unsigned short* __restrict__ Kl_g,
                     unsigned short* __restrict__ Vh_g,
                     unsigned short* __restrict__ Vl_g,
                     float* __restrict__ Dout)
{
    __shared__ unsigned short sAh[128 * LDK];
    __shared__ unsigned short sAl[128 * LDK];
    __shared__ unsigned short sBh[128 * LDK];
    __shared__ unsigned short sBl[128 * LDK];

    const int tid  = threadIdx.x;
    const int lane = tid & 63;

    int proj = 0, nloc;
    if (MODE == 0) { proj = blockIdx.x >> 3; nloc = (blockIdx.x & 7) * 128; }
    else           { nloc = blockIdx.x * 128; }
    const int m0 = blockIdx.y * 128;

    const unsigned short* __restrict__ Wh = Wh_g + (size_t)proj * D_MODEL * D_MODEL;
    const unsigned short* __restrict__ Wl = Wl_g + (size_t)proj * D_MODEL * D_MODEL;

    const int srow = tid >> 1;
    const int sseg = (tid & 1) * 16;

    const int wr = ((tid >> 6) >> 1) * 64;
    const int wc = ((tid >> 6) & 1) * 64;

    f32x4 acc[4][4];
    #pragma unroll
    for (int i = 0; i < 4; ++i)
        #pragma unroll
        for (int j = 0; j < 4; ++j) {
            acc[i][j][0] = 0.f; acc[i][j][1] = 0.f;
            acc[i][j][2] = 0.f; acc[i][j][3] = 0.f;
        }

    const size_t a_row = (size_t)(m0   + srow) * D_MODEL + sseg;
    const size_t b_row = (size_t)(nloc + srow) * D_MODEL + sseg;

    for (int kt = 0; kt < D_MODEL; kt += 32) {
        uint4 ah0 = *(const uint4*)&Ah_g[a_row + kt];
        uint4 ah1 = *(const uint4*)&Ah_g[a_row + kt + 8];
        uint4 al0 = *(const uint4*)&Al_g[a_row + kt];
        uint4 al1 = *(const uint4*)&Al_g[a_row + kt + 8];
        uint4 bh0 = *(const uint4*)&Wh[b_row + kt];
        uint4 bh1 = *(const uint4*)&Wh[b_row + kt + 8];
        uint4 bl0 = *(const uint4*)&Wl[b_row + kt];
        uint4 bl1 = *(const uint4*)&Wl[b_row + kt + 8];
        __syncthreads();
        *(uint4*)&sAh[srow * LDK + sseg]     = ah0;
        *(uint4*)&sAh[srow * LDK + sseg + 8] = ah1;
        *(uint4*)&sAl[srow * LDK + sseg]     = al0;
        *(uint4*)&sAl[srow * LDK + sseg + 8] = al1;
        *(uint4*)&sBh[srow * LDK + sseg]     = bh0;
        *(uint4*)&sBh[srow * LDK + sseg + 8] = bh1;
        *(uint4*)&sBl[srow * LDK + sseg]     = bl0;
        *(uint4*)&sBl[srow * LDK + sseg + 8] = bl1;
        __syncthreads();

        const int fr = lane & 15;
        const int ko = (lane >> 4) * 8;
        bf16x8 fah[4], fal[4], fbh[4], fbl[4];
        #pragma unroll
        for (int i = 0; i < 4; ++i) {
            fah[i] = *(const bf16x8*)&sAh[(wr + i*16 + fr) * LDK + ko];
            fal[i] = *(const bf16x8*)&sAl[(wr + i*16 + fr) * LDK + ko];
            fbh[i] = *(const bf16x8*)&sBh[(wc + i*16 + fr) * LDK + ko];
            fbl[i] = *(const bf16x8*)&sBl[(wc + i*16 + fr) * LDK + ko];
        }
        #pragma unroll
        for (int mi = 0; mi < 4; ++mi)
            #pragma unroll
            for (int ni = 0; ni < 4; ++ni) {
                acc[mi][ni] = __builtin_amdgcn_mfma_f32_16x16x32_bf16(fah[mi], fbh[ni], acc[mi][ni], 0, 0, 0);
                acc[mi][ni] = __builtin_amdgcn_mfma_f32_16x16x32_bf16(fah[mi], fbl[ni], acc[mi][ni], 0, 0, 0);
                acc[mi][ni] = __builtin_amdgcn_mfma_f32_16x16x32_bf16(fal[mi], fbh[ni], acc[mi][ni], 0, 0, 0);
            }
    }

    // Epilogue. C/D frag layout: col = lane&15, row = (lane>>4)*4 + reg.
    const int fcol  = lane & 15;
    const int frow0 = (lane >> 4) * 4;
    #pragma unroll
    for (int mi = 0; mi < 4; ++mi) {
        const int m_base = m0 + wr + mi * 16 + frow0;
        #pragma unroll
        for (int ni = 0; ni < 4; ++ni) {
            const int n = nloc + wc + ni * 16 + fcol;
            if (MODE == 1) {
                #pragma unroll
                for (int r = 0; r < 4; ++r)
                    Dout[(size_t)(m_base + r) * D_MODEL + n] = acc[mi][ni][r];
            } else {
                const int h = n >> 6;
                const int d = n & 63;
                if (proj == 2) {
                    unsigned short vh[4], vl[4];
                    #pragma unroll
                    for (int r = 0; r < 4; ++r) {
                        float v = acc[mi][ni][r];
                        vh[r] = f32_to_bf16_rne(v);
                        vl[r] = f32_to_bf16_rne(v - bf16_to_f32(vh[r]));
                    }
                    const int b = m_base >> 11;
                    const int s = m_base & (SEQ - 1);
                    const size_t addr =
                        ((size_t)(b * NUM_HEADS + h) * HEAD_DIM + d) * SEQ + s;
                    *(uint2*)&Vh_g[addr] = make_uint2(
                        (unsigned)vh[0] | ((unsigned)vh[1] << 16),
                        (unsigned)vh[2] | ((unsigned)vh[3] << 16));
                    *(uint2*)&Vl_g[addr] = make_uint2(
                        (unsigned)vl[0] | ((unsigned)vl[1] << 16),
                        (unsigned)vl[2] | ((unsigned)vl[3] << 16));
                } else {
                    #pragma unroll
                    for (int r = 0; r < 4; ++r) {
                        const int m = m_base + r;
                        const int b = m >> 11;
                        const int s = m & (SEQ - 1);
                        float v = acc[mi][ni][r];
                        const float other = __shfl_xor(v, 1);
                        const float c  = cos_t[s * 32 + (d >> 1)];
                        const float sn = sin_t[s * 32 + (d >> 1)];
                        float res = (d & 1) ? fmaf(other, sn, v * c)
                                            : fmaf(-other, sn, v * c);
                        if (proj == 0) res *= 0.125f;   // fold 1/sqrt(64) into Q
                        unsigned short hi = f32_to_bf16_rne(res);
                        unsigned short lo = f32_to_bf16_rne(res - bf16_to_f32(hi));
                        const size_t addr =
                            ((size_t)(b * NUM_HEADS + h) * SEQ + s) * HEAD_DIM + d;
                        if (proj == 0) { Qh_g[addr] = hi; Ql_g[addr] = lo; }
                        else           { Kh_g[addr] = hi; Kl_g[addr] = lo; }
                    }
                }
            }
        }
    }
}

// ---------------------------------------------------------------------------
// Flash attention v3 = v2 compute path (validated R5) + two structural fixes:
//  * PAIRED q-blocks: 512 blocks, each runs q-block pb then 15-pb -> every
//    block stages exactly 68 tiles; per-CU work is uniform (fixes the 13.6%
//    occupancy / CU-imbalance seen in R5).
//  * LDS double-buffer: one barrier per tile (stage next tile into buf^1
//    after computing buf), plus s_setprio around MFMA clusters (T5).
// ---------------------------------------------------------------------------
#define KSTR 72   // sK row stride in shorts (32 keys x 64 d + pad)
#define VSTR 40   // sV row stride in shorts (64 d x 32 keys + pad)

__global__ __launch_bounds__(256)
void attn_mfma3_kernel(const unsigned short* __restrict__ Qh_g,  // [bh][S][64]
                       const unsigned short* __restrict__ Ql_g,
                       const unsigned short* __restrict__ Kh_g,  // [bh][S][64]
                       const unsigned short* __restrict__ Kl_g,
                       const unsigned short* __restrict__ Vh_g,  // [bh][64][S]
                       const unsigned short* __restrict__ Vl_g,
                       unsigned short* __restrict__ attn_h,      // [B*S][1024]
                       unsigned short* __restrict__ attn_l)
{
    __shared__ unsigned short sKh[2][32 * KSTR];
    __shared__ unsigned short sKl[2][32 * KSTR];
    __shared__ unsigned short sVh[2][64 * VSTR];
    __shared__ unsigned short sVl[2][64 * VSTR];

    // grid: 512 = 64 bh x 8 pair-blocks. XCD-chunked: 8 bh per XCD.
    const int bid = blockIdx.x;
    const int swz = (bid & 7) * 64 + (bid >> 3);
    const int bh  = swz >> 3;        // 0..63
    const int pb  = swz & 7;         // pair id 0..7

    const int tid   = threadIdx.x;
    const int lane  = tid & 63;
    const int wv    = tid >> 6;          // wave 0..3
    const int lq    = lane & 31;         // q within wave tile (S^T col)
    const int hi5   = lane >> 5;         // 0/1
    const bool lo32 = (hi5 == 0);

    // ---- staging map (256 threads, one 32-key tile) ----
    const int skey = tid >> 3, sdseg = (tid & 7) * 8;       // K: [32 keys][64 d]
    const int svd  = tid >> 2, svseg = (tid & 3) * 8;       // V: [64 d][32 keys]
    const size_t kg_base = ((size_t)bh * SEQ + skey) * HEAD_DIM + sdseg;
    const size_t vg_base = ((size_t)bh * HEAD_DIM + svd) * SEQ + svseg;

    const int b  = bh >> 4;
    const int hh = bh & 15;

    #pragma unroll 1
    for (int pass = 0; pass < 2; ++pass) {
        const int qb   = pass ? (15 - pb) : pb;
        const int q0   = qb * 128 + wv * 32;     // wave's first q row
        const int diag = qb * 4 + wv;            // wave's diagonal tile index
        const int nt   = (qb + 1) * 4;           // tiles this block stages

        // ---- Q B-frags (hi/lo), 4 k-steps of 16 d. Pre-roped, pre-scaled. ----
        const size_t qrow_base = ((size_t)bh * SEQ + q0 + lq) * HEAD_DIM;
        bf16x8 qfh[4], qfl[4];
        #pragma unroll
        for (int kt = 0; kt < 4; ++kt) {
            qfh[kt] = *(const bf16x8*)&Qh_g[qrow_base + kt * 16 + hi5 * 8];
            qfl[kt] = *(const bf16x8*)&Ql_g[qrow_base + kt * 16 + hi5 * 8];
        }

        f32x16 oacc0, oacc1;
        #pragma unroll
        for (int r = 0; r < 16; ++r) { oacc0[r] = 0.f; oacc1[r] = 0.f; }
        float m_st = -INFINITY;   // running max for q = lq
        float l_st = 0.f;         // running denom for q = lq

        // prologue: stage tile 0 into buffer 0
        {
            uint4 kh = *(const uint4*)&Kh_g[kg_base];
            uint4 kl = *(const uint4*)&Kl_g[kg_base];
            uint4 vh = *(const uint4*)&Vh_g[vg_base];
            uint4 vl = *(const uint4*)&Vl_g[vg_base];
            *(uint4*)&sKh[0][skey * KSTR + sdseg] = kh;
            *(uint4*)&sKl[0][skey * KSTR + sdseg] = kl;
            *(uint4*)&sVh[0][svd * VSTR + svseg]  = vh;
            *(uint4*)&sVl[0][svd * VSTR + svseg]  = vl;
        }
        __syncthreads();

        uint4 r_kh, r_kl, r_vh, r_vl;
        for (int t = 0; t < nt; ++t) {
            const int cur = t & 1;
            // issue next tile's loads early (land during compute)
            if (t + 1 < nt) {
                const size_t koff = (size_t)(t + 1) * 32 * HEAD_DIM;
                const size_t voff = (size_t)(t + 1) * 32;
                r_kh = *(const uint4*)&Kh_g[kg_base + koff];
                r_kl = *(const uint4*)&Kl_g[kg_base + koff];
                r_vh = *(const uint4*)&Vh_g[vg_base + voff];
                r_vl = *(const uint4*)&Vl_g[vg_base + voff];
            }

            if (t <= diag) {   // wave-uniform: skip fully-masked tiles
                // ---- QK^T: S^T[key][q] = sum_d K[key][d] Q[q][d] ----
                f32x16 S;
                #pragma unroll
                for (int r = 0; r < 16; ++r) S[r] = 0.f;
                __builtin_amdgcn_s_setprio(1);
                #pragma unroll
                for (int kt = 0; kt < 4; ++kt) {
                    const int ko = (lane & 31) * KSTR + kt * 16 + hi5 * 8;
                    bf16x8 kh = *(const bf16x8*)&sKh[cur][ko];
                    bf16x8 kl = *(const bf16x8*)&sKl[cur][ko];
                    S = __builtin_amdgcn_mfma_f32_32x32x16_bf16(kh, qfh[kt], S, 0, 0, 0);
                    S = __builtin_amdgcn_mfma_f32_32x32x16_bf16(kh, qfl[kt], S, 0, 0, 0);
                    S = __builtin_amdgcn_mfma_f32_32x32x16_bf16(kl, qfh[kt], S, 0, 0, 0);
                }
                __builtin_amdgcn_s_setprio(0);

                // causal mask on the diagonal tile: key_local > q_local -> -inf
                if (t == diag) {
                    #pragma unroll
                    for (int r = 0; r < 16; ++r) {
                        const int keyl = (r & 3) + 8 * (r >> 2) + 4 * hi5;
                        if (keyl > lq) S[r] = -INFINITY;
                    }
                }

                // ---- online softmax (q = lq; row split across lane, lane^32) --
                float pmax = S[0];
                #pragma unroll
                for (int r = 1; r < 16; ++r) pmax = fmaxf(pmax, S[r]);
                pmax = fmaxf(pmax, __shfl_xor(pmax, 32));

                if (__any(pmax > m_st + 8.0f)) {       // rescale path (rare)
                    const float mnew = fmaxf(m_st, pmax);
                    const float corr = __expf(m_st - mnew);   // 0 on first tile
                    m_st = mnew;
                    l_st *= corr;
                    #pragma unroll
                    for (int r = 0; r < 16; ++r) {
                        const int qrow = (r & 3) + 8 * (r >> 2) + 4 * hi5;
                        const float c_o = __shfl(corr, qrow);  // corr of that q-row
                        oacc0[r] *= c_o;
                        oacc1[r] *= c_o;
                    }
                }

                float psum = 0.f;
                #pragma unroll
                for (int r = 0; r < 16; ++r) {
                    S[r] = __expf(S[r] - m_st);
                    psum += S[r];
                }
                psum += __shfl_xor(psum, 32);
                l_st += psum;

                // ---- P -> A-frags (hi/lo) via cvt_pk + shfl_xor(32) ----
                #pragma unroll
                for (int h = 0; h < 2; ++h) {          // 16-key halves
                    const int r0 = h * 8;
                    unsigned int Xh[4], Xl[4];
                    #pragma unroll
                    for (int c = 0; c < 4; ++c) {
                        const float p0 = S[r0 + 2*c], p1 = S[r0 + 2*c + 1];
                        Xh[c] = cvt_pk_bf16(p0, p1);
                        const float l0 = p0 - __uint_as_float(Xh[c] << 16);
                        const float l1 = p1 - __uint_as_float(Xh[c] & 0xFFFF0000u);
                        Xl[c] = cvt_pk_bf16(l0, l1);
                    }
                    unsigned int Yh[4], Yl[4];
                    #pragma unroll
                    for (int c = 0; c < 4; ++c) {
                        Yh[c] = (unsigned int)__shfl_xor((int)Xh[c], 32);
                        Yl[c] = (unsigned int)__shfl_xor((int)Xl[c], 32);
                    }
                    union { unsigned int u[4]; bf16x8 v; } pah, pal;
                    pah.u[0] = lo32 ? Xh[0] : Yh[2];
                    pah.u[1] = lo32 ? Xh[1] : Yh[3];
                    pah.u[2] = lo32 ? Yh[0] : Xh[2];
                    pah.u[3] = lo32 ? Yh[1] : Xh[3];
                    pal.u[0] = lo32 ? Xl[0] : Yl[2];
                    pal.u[1] = lo32 ? Xl[1] : Yl[3];
                    pal.u[2] = lo32 ? Yl[0] : Xl[2];
                    pal.u[3] = lo32 ? Yl[1] : Xl[3];

                    // ---- PV: O[q][d] += P[q][keys] V[keys][d] ----
                    const int vo0 = (0 * 32 + (lane & 31)) * VSTR + h * 16 + hi5 * 8;
                    const int vo1 = (1 * 32 + (lane & 31)) * VSTR + h * 16 + hi5 * 8;
                    bf16x8 vh0 = *(const bf16x8*)&sVh[cur][vo0];
                    bf16x8 vl0 = *(const bf16x8*)&sVl[cur][vo0];
                    bf16x8 vh1 = *(const bf16x8*)&sVh[cur][vo1];
                    bf16x8 vl1 = *(const bf16x8*)&sVl[cur][vo1];
                    __builtin_amdgcn_s_setprio(1);
                    oacc0 = __builtin_amdgcn_mfma_f32_32x32x16_bf16(pah.v, vh0, oacc0, 0, 0, 0);
                    oacc0 = __builtin_amdgcn_mfma_f32_32x32x16_bf16(pah.v, vl0, oacc0, 0, 0, 0);
                    oacc0 = __builtin_amdgcn_mfma_f32_32x32x16_bf16(pal.v, vh0, oacc0, 0, 0, 0);
                    oacc1 = __builtin_amdgcn_mfma_f32_32x32x16_bf16(pah.v, vh1, oacc1, 0, 0, 0);
                    oacc1 = __builtin_amdgcn_mfma_f32_32x32x16_bf16(pah.v, vl1, oacc1, 0, 0, 0);
                    oacc1 = __builtin_amdgcn_mfma_f32_32x32x16_bf16(pal.v, vh1, oacc1, 0, 0, 0);
                    __builtin_amdgcn_s_setprio(0);
                }
            }

            // stage next tile into the other buffer (prev tile's readers are
            // past the barrier at the end of the previous iteration)
            if (t + 1 < nt) {
                *(uint4*)&sKh[cur ^ 1][skey * KSTR + sdseg] = r_kh;
                *(uint4*)&sKl[cur ^ 1][skey * KSTR + sdseg] = r_kl;
                *(uint4*)&sVh[cur ^ 1][svd * VSTR + svseg]  = r_vh;
                *(uint4*)&sVl[cur ^ 1][svd * VSTR + svseg]  = r_vl;
            }
            __syncthreads();
        }

        // ---- epilogue: normalize, split hi/lo, store [b][s][h*64+d] ----
        const float linv = 1.0f / l_st;
        #pragma unroll
        for (int r = 0; r < 16; ++r) {
            const int qrow = (r & 3) + 8 * (r >> 2) + 4 * hi5;
            const float li = __shfl(linv, qrow);
            const int s = q0 + qrow;
            const size_t rowb = ((size_t)b * SEQ + s) * D_MODEL + hh * HEAD_DIM;
            const float v0 = oacc0[r] * li;
            const float v1 = oacc1[r] * li;
            const unsigned short h0 = f32_to_bf16_rne(v0);
            const unsigned short h1 = f32_to_bf16_rne(v1);
            attn_h[rowb + (lane & 31)]      = h0;
            attn_h[rowb + 32 + (lane & 31)] = h1;
            attn_l[rowb + (lane & 31)]      = f32_to_bf16_rne(v0 - bf16_to_f32(h0));
            attn_l[rowb + 32 + (lane & 31)] = f32_to_bf16_rne(v1 - bf16_to_f32(h1));
        }
    }
}

// ---------------------------------------------------------------------------
extern "C" void kernel_launch(void* const* d_in, const int* in_sizes, int n_in,
                              void* d_out, int out_size, void* d_ws, size_t ws_size,
                              hipStream_t stream) {
    const float* wq  = (const float*)d_in[0];
    const float* wk  = (const float*)d_in[1];
    const float* wv  = (const float*)d_in[2];
    const float* wo  = (const float*)d_in[3];
    const float* x   = (const float*)d_in[4];
    const int*   pos = (const int*)d_in[5];   // jax default: int32
    float* out = (float*)d_out;

    // workspace carve-up (~152 MiB)
    const size_t QKV_BYTES = (size_t)BATCH * NUM_HEADS * SEQ * HEAD_DIM * 2; // 16.78MB
    char* ws = (char*)d_ws;
    unsigned short* Qh  = (unsigned short*)ws; ws += QKV_BYTES;
    unsigned short* Ql  = (unsigned short*)ws; ws += QKV_BYTES;
    unsigned short* Kh  = (unsigned short*)ws; ws += QKV_BYTES;
    unsigned short* Kl  = (unsigned short*)ws; ws += QKV_BYTES;
    unsigned short* Vth = (unsigned short*)ws; ws += QKV_BYTES;
    unsigned short* Vtl = (unsigned short*)ws; ws += QKV_BYTES;
    unsigned short* xh  = (unsigned short*)ws; ws += QKV_BYTES;
    unsigned short* xl  = (unsigned short*)ws; ws += QKV_BYTES;
    unsigned short* wh  = (unsigned short*)ws; ws += (size_t)4 * 1024 * 1024 * 2;
    unsigned short* wl  = (unsigned short*)ws; ws += (size_t)4 * 1024 * 1024 * 2;
    float* cos_t = (float*)ws;                 ws += (size_t)SEQ * 32 * 4;
    float* sin_t = (float*)ws;                 ws += (size_t)SEQ * 32 * 4;
    // xh/xl dead after QKV GEMM -> reuse as attention output hi/lo
    unsigned short* attn_h = xh;
    unsigned short* attn_l = xl;

    rope_table_kernel<<<(SEQ * 32 + 255) / 256, 256, 0, stream>>>(pos, cos_t, sin_t);

    // pre-split inputs into hi/lo bf16
    split_kernel<<<(2097152 + 255) / 256, 256, 0, stream>>>(x, xh, xl, 2097152);
    split_kernel<<<(262144 + 255) / 256, 256, 0, stream>>>(wq, wh,           wl,           262144);
    split_kernel<<<(262144 + 255) / 256, 256, 0, stream>>>(wk, wh + 1048576, wl + 1048576, 262144);
    split_kernel<<<(262144 + 255) / 256, 256, 0, stream>>>(wv, wh + 2097152, wl + 2097152, 262144);
    split_kernel<<<(262144 + 255) / 256, 256, 0, stream>>>(wo, wh + 3145728, wl + 3145728, 262144);

    // QKV projection + RoPE + split + V-transpose (MFMA, split precision)
    mfma_split_gemm<0><<<dim3(24, 64), 256, 0, stream>>>(
        xh, xl, wh, wl, cos_t, sin_t, Qh, Ql, Kh, Kl, Vth, Vtl, nullptr);

    // causal flash attention v3 (paired q-blocks + LDS dbuf)
    attn_mfma3_kernel<<<dim3(512), 256, 0, stream>>>(
        Qh, Ql, Kh, Kl, Vth, Vtl, attn_h, attn_l);

    // output projection (MFMA, split precision)
    mfma_split_gemm<1><<<dim3(8, 64), 256, 0, stream>>>(
        attn_h, attn_l, wh + 3145728, wl + 3145728, cos_t, sin_t,
        nullptr, nullptr, nullptr, nullptr, nullptr, nullptr, out);
}

// Round 7
// 479.864 us; speedup vs baseline: 8.2517x; 1.0447x over previous
//
#include <hip/hip_runtime.h>
#include <hip/hip_bf16.h>
#include <math.h>

// Problem constants (fixed by the reference)
#define D_MODEL   1024
#define NUM_HEADS 16
#define HEAD_DIM  64
#define BATCH     4
#define SEQ       2048
#define THETA     10000.0
#define M_TOTAL   (BATCH * SEQ)          // 8192 rows

typedef __attribute__((ext_vector_type(8)))  short bf16x8;   // 8 bf16 = 4 VGPR
typedef __attribute__((ext_vector_type(4)))  float f32x4;
typedef __attribute__((ext_vector_type(16))) float f32x16;

// ---------------------------------------------------------------------------
// fp32 <-> bf16 split helpers (RNE). a = hi + lo with |a - hi - lo| <= 2^-18|a|
// ---------------------------------------------------------------------------
__device__ __forceinline__ unsigned short f32_to_bf16_rne(float f) {
    unsigned int u = __float_as_uint(f);
    u += 0x7FFFu + ((u >> 16) & 1u);
    return (unsigned short)(u >> 16);
}
__device__ __forceinline__ float bf16_to_f32(unsigned short h) {
    return __uint_as_float(((unsigned int)h) << 16);
}
// packed pair: lo half = bf16(a), hi half = bf16(b)
__device__ __forceinline__ unsigned int cvt_pk_bf16(float a, float b) {
    unsigned int r;
    asm volatile("v_cvt_pk_bf16_f32 %0, %1, %2" : "=v"(r) : "v"(a), "v"(b));
    return r;
}

// ---------------------------------------------------------------------------
// RoPE cos/sin table: [SEQ][32] each, double-precision angle generation.
// ---------------------------------------------------------------------------
__global__ void rope_table_kernel(const int* __restrict__ pos,
                                  float* __restrict__ cos_t,
                                  float* __restrict__ sin_t) {
    int idx = blockIdx.x * blockDim.x + threadIdx.x;   // s*32 + i
    if (idx >= SEQ * 32) return;
    int s = idx >> 5;
    int i = idx & 31;
    double inv = pow((double)THETA, -((double)(2 * i)) / (double)HEAD_DIM);
    double ang = (double)pos[s] * inv;
    cos_t[idx] = (float)cos(ang);
    sin_t[idx] = (float)sin(ang);
}

// ---------------------------------------------------------------------------
// Split fp32 array -> hi/lo bf16 arrays (same layout). One float4 per thread.
// ---------------------------------------------------------------------------
__global__ void split_kernel(const float* __restrict__ src,
                             unsigned short* __restrict__ hi,
                             unsigned short* __restrict__ lo,
                             int n4) {
    int i = blockIdx.x * blockDim.x + threadIdx.x;
    if (i >= n4) return;
    float4 f = ((const float4*)src)[i];
    float fv[4] = {f.x, f.y, f.z, f.w};
    unsigned int hw[2], lw[2];
    #pragma unroll
    for (int j = 0; j < 2; ++j) {
        unsigned short h0 = f32_to_bf16_rne(fv[2*j]);
        unsigned short h1 = f32_to_bf16_rne(fv[2*j+1]);
        unsigned short l0 = f32_to_bf16_rne(fv[2*j]   - bf16_to_f32(h0));
        unsigned short l1 = f32_to_bf16_rne(fv[2*j+1] - bf16_to_f32(h1));
        hw[j] = (unsigned int)h0 | ((unsigned int)h1 << 16);
        lw[j] = (unsigned int)l0 | ((unsigned int)l1 << 16);
    }
    ((uint2*)hi)[i] = make_uint2(hw[0], hw[1]);
    ((uint2*)lo)[i] = make_uint2(lw[0], lw[1]);
}

// ---------------------------------------------------------------------------
// Split-precision MFMA GEMM v2: same math/epilogue as the R3-validated kernel
// (Ahi*Bhi + Ahi*Blo + Alo*Bhi, 3x mfma_f32_16x16x32_bf16), new staging:
//  * global_load_lds w=16: linear LDS [128][32] shorts per array (32 KB total),
//    XOR-swizzled CONTENT via pre-swizzled per-lane global source (rule 21):
//    LDS (row, chunk c) holds global chunk (row, c ^ (row&3)); frag reads
//    apply the same XOR -> ~2-way residual bank aliasing (free).
//  * 1D grid, XCD-chunked: xcd = bid&7 owns mblk in [xcd*8, xcd*8+8) x all
//    nblk (W-panel-inner order) -> A-chunk resident in that XCD's L2.
// MODE 0: N-space = 3*1024 (Q|K|V); RoPE epilogue; V transposed [bh][64][S].
// MODE 1: plain fp32 write to Dout.
// ---------------------------------------------------------------------------
template<int MODE>
__global__ __launch_bounds__(256)
void mfma_split_gemm2(const unsigned short* __restrict__ Ah_g,   // [8192][1024]
                      const unsigned short* __restrict__ Al_g,
                      const unsigned short* __restrict__ Wh_g,   // [.][1024][1024]
                      const unsigned short* __restrict__ Wl_g,
                      const float* __restrict__ cos_t,
                      const float* __restrict__ sin_t,
                      unsigned short* __restrict__ Qh_g,
                      unsigned short* __restrict__ Ql_g,
                      unsigned short* __restrict__ Kh_g,
                      unsigned short* __restrict__ Kl_g,
                      unsigned short* __restrict__ Vh_g,
                      unsigned short* __restrict__ Vl_g,
                      float* __restrict__ Dout)
{
    __shared__ unsigned short sAh[128 * 32];
    __shared__ unsigned short sAl[128 * 32];
    __shared__ unsigned short sBh[128 * 32];
    __shared__ unsigned short sBl[128 * 32];

    const int tid  = threadIdx.x;
    const int lane = tid & 63;
    const int wvid = tid >> 6;

    // XCD-chunked decode (grid = 8 XCDs x (nblk x 8 mblk))
    const int bid = blockIdx.x;
    const int xcd = bid & 7;
    const int idx = bid >> 3;
    const int mblk = xcd * 8 + (idx & 7);
    const int nblk = idx >> 3;                  // MODE0: 0..23, MODE1: 0..7
    int proj = 0, nloc;
    if (MODE == 0) { proj = nblk >> 3; nloc = (nblk & 7) * 128; }
    else           { nloc = nblk * 128; }
    const int m0 = mblk * 128;

    const unsigned short* __restrict__ Wh = Wh_g + (size_t)proj * D_MODEL * D_MODEL;
    const unsigned short* __restrict__ Wl = Wl_g + (size_t)proj * D_MODEL * D_MODEL;

    // wave -> 64x64 output quadrant
    const int wr = (wvid >> 1) * 64;
    const int wc = (wvid & 1) * 64;

    // ---- staging map: wave stages rows [wvid*32, wvid*32+32) of each array,
    // two 16-row issues per array. lane l -> dest (row r0+ (l>>2), chunk l&3);
    // source chunk = (l&3) ^ ((l>>2)&3)  (inverse == forward, involution).
    const int r0 = wvid * 32;
    const int sr = lane >> 2;                              // 0..15
    const int sc = (((lane & 3) ^ (sr & 3)) << 3);         // swizzled src col, shorts
    const size_t a_src0 = (size_t)(m0 + r0 + sr) * D_MODEL + sc;
    const size_t a_src1 = a_src0 + (size_t)16 * D_MODEL;
    const size_t b_src0 = (size_t)(nloc + r0 + sr) * D_MODEL + sc;
    const size_t b_src1 = b_src0 + (size_t)16 * D_MODEL;

    f32x4 acc[4][4];
    #pragma unroll
    for (int i = 0; i < 4; ++i)
        #pragma unroll
        for (int j = 0; j < 4; ++j) {
            acc[i][j][0] = 0.f; acc[i][j][1] = 0.f;
            acc[i][j][2] = 0.f; acc[i][j][3] = 0.f;
        }

    // frag read map: row f = (wr|wc) + i*16 + fr; 16B chunk = g ^ (fr&3)
    const int fr  = lane & 15;
    const int g   = lane >> 4;
    const int sw8 = ((g ^ (fr & 3)) << 3);                 // shorts

    for (int kt = 0; kt < D_MODEL; kt += 32) {
        // async stage: 8 global_load_lds per wave (4 arrays x 2 issues)
        __builtin_amdgcn_global_load_lds((const void*)(Ah_g + a_src0 + kt),
                                         (void*)&sAh[r0 * 32],        16, 0, 0);
        __builtin_amdgcn_global_load_lds((const void*)(Ah_g + a_src1 + kt),
                                         (void*)&sAh[(r0 + 16) * 32], 16, 0, 0);
        __builtin_amdgcn_global_load_lds((const void*)(Al_g + a_src0 + kt),
                                         (void*)&sAl[r0 * 32],        16, 0, 0);
        __builtin_amdgcn_global_load_lds((const void*)(Al_g + a_src1 + kt),
                                         (void*)&sAl[(r0 + 16) * 32], 16, 0, 0);
        __builtin_amdgcn_global_load_lds((const void*)(Wh + b_src0 + kt),
                                         (void*)&sBh[r0 * 32],        16, 0, 0);
        __builtin_amdgcn_global_load_lds((const void*)(Wh + b_src1 + kt),
                                         (void*)&sBh[(r0 + 16) * 32], 16, 0, 0);
        __builtin_amdgcn_global_load_lds((const void*)(Wl + b_src0 + kt),
                                         (void*)&sBl[r0 * 32],        16, 0, 0);
        __builtin_amdgcn_global_load_lds((const void*)(Wl + b_src1 + kt),
                                         (void*)&sBl[(r0 + 16) * 32], 16, 0, 0);
        __syncthreads();   // drains vmcnt(0): tile staged, all waves synced

        bf16x8 fah[4], fal[4], fbh[4], fbl[4];
        #pragma unroll
        for (int i = 0; i < 4; ++i) {
            fah[i] = *(const bf16x8*)&sAh[(wr + i*16 + fr) * 32 + sw8];
            fal[i] = *(const bf16x8*)&sAl[(wr + i*16 + fr) * 32 + sw8];
            fbh[i] = *(const bf16x8*)&sBh[(wc + i*16 + fr) * 32 + sw8];
            fbl[i] = *(const bf16x8*)&sBl[(wc + i*16 + fr) * 32 + sw8];
        }
        #pragma unroll
        for (int mi = 0; mi < 4; ++mi)
            #pragma unroll
            for (int ni = 0; ni < 4; ++ni) {
                acc[mi][ni] = __builtin_amdgcn_mfma_f32_16x16x32_bf16(fah[mi], fbh[ni], acc[mi][ni], 0, 0, 0);
                acc[mi][ni] = __builtin_amdgcn_mfma_f32_16x16x32_bf16(fah[mi], fbl[ni], acc[mi][ni], 0, 0, 0);
                acc[mi][ni] = __builtin_amdgcn_mfma_f32_16x16x32_bf16(fal[mi], fbh[ni], acc[mi][ni], 0, 0, 0);
            }
        __syncthreads();   // all reads done before next tile overwrites
    }

    // Epilogue (identical to validated R3). C/D: col = lane&15, row = (lane>>4)*4+reg.
    const int fcol  = lane & 15;
    const int frow0 = (lane >> 4) * 4;
    #pragma unroll
    for (int mi = 0; mi < 4; ++mi) {
        const int m_base = m0 + wr + mi * 16 + frow0;
        #pragma unroll
        for (int ni = 0; ni < 4; ++ni) {
            const int n = nloc + wc + ni * 16 + fcol;
            if (MODE == 1) {
                #pragma unroll
                for (int r = 0; r < 4; ++r)
                    Dout[(size_t)(m_base + r) * D_MODEL + n] = acc[mi][ni][r];
            } else {
                const int h = n >> 6;
                const int d = n & 63;
                if (proj == 2) {
                    unsigned short vh[4], vl[4];
                    #pragma unroll
                    for (int r = 0; r < 4; ++r) {
                        float v = acc[mi][ni][r];
                        vh[r] = f32_to_bf16_rne(v);
                        vl[r] = f32_to_bf16_rne(v - bf16_to_f32(vh[r]));
                    }
                    const int b = m_base >> 11;
                    const int s = m_base & (SEQ - 1);
                    const size_t addr =
                        ((size_t)(b * NUM_HEADS + h) * HEAD_DIM + d) * SEQ + s;
                    *(uint2*)&Vh_g[addr] = make_uint2(
                        (unsigned)vh[0] | ((unsigned)vh[1] << 16),
                        (unsigned)vh[2] | ((unsigned)vh[3] << 16));
                    *(uint2*)&Vl_g[addr] = make_uint2(
                        (unsigned)vl[0] | ((unsigned)vl[1] << 16),
                        (unsigned)vl[2] | ((unsigned)vl[3] << 16));
                } else {
                    #pragma unroll
                    for (int r = 0; r < 4; ++r) {
                        const int m = m_base + r;
                        const int b = m >> 11;
                        const int s = m & (SEQ - 1);
                        float v = acc[mi][ni][r];
                        const float other = __shfl_xor(v, 1);
                        const float c  = cos_t[s * 32 + (d >> 1)];
                        const float sn = sin_t[s * 32 + (d >> 1)];
                        float res = (d & 1) ? fmaf(other, sn, v * c)
                                            : fmaf(-other, sn, v * c);
                        if (proj == 0) res *= 0.125f;   // fold 1/sqrt(64) into Q
                        unsigned short hi = f32_to_bf16_rne(res);
                        unsigned short lo = f32_to_bf16_rne(res - bf16_to_f32(hi));
                        const size_t addr =
                            ((size_t)(b * NUM_HEADS + h) * SEQ + s) * HEAD_DIM + d;
                        if (proj == 0) { Qh_g[addr] = hi; Ql_g[addr] = lo; }
                        else           { Kh_g[addr] = hi; Kl_g[addr] = lo; }
                    }
                }
            }
        }
    }
}

// ---------------------------------------------------------------------------
// Flash attention v3 (validated R6): paired q-blocks (uniform per-CU work),
// LDS double-buffer (one barrier/tile), setprio around MFMA clusters.
// ---------------------------------------------------------------------------
#define KSTR 72   // sK row stride in shorts (32 keys x 64 d + pad)
#define VSTR 40   // sV row stride in shorts (64 d x 32 keys + pad)

__global__ __launch_bounds__(256)
void attn_mfma3_kernel(const unsigned short* __restrict__ Qh_g,  // [bh][S][64]
                       const unsigned short* __restrict__ Ql_g,
                       const unsigned short* __restrict__ Kh_g,  // [bh][S][64]
                       const unsigned short* __restrict__ Kl_g,
                       const unsigned short* __restrict__ Vh_g,  // [bh][64][S]
                       const unsigned short* __restrict__ Vl_g,
                       unsigned short* __restrict__ attn_h,      // [B*S][1024]
                       unsigned short* __restrict__ attn_l)
{
    __shared__ unsigned short sKh[2][32 * KSTR];
    __shared__ unsigned short sKl[2][32 * KSTR];
    __shared__ unsigned short sVh[2][64 * VSTR];
    __shared__ unsigned short sVl[2][64 * VSTR];

    // grid: 512 = 64 bh x 8 pair-blocks. XCD-chunked: 8 bh per XCD.
    const int bid = blockIdx.x;
    const int swz = (bid & 7) * 64 + (bid >> 3);
    const int bh  = swz >> 3;        // 0..63
    const int pb  = swz & 7;         // pair id 0..7

    const int tid   = threadIdx.x;
    const int lane  = tid & 63;
    const int wv    = tid >> 6;          // wave 0..3
    const int lq    = lane & 31;         // q within wave tile (S^T col)
    const int hi5   = lane >> 5;         // 0/1
    const bool lo32 = (hi5 == 0);

    // ---- staging map (256 threads, one 32-key tile) ----
    const int skey = tid >> 3, sdseg = (tid & 7) * 8;       // K: [32 keys][64 d]
    const int svd  = tid >> 2, svseg = (tid & 3) * 8;       // V: [64 d][32 keys]
    const size_t kg_base = ((size_t)bh * SEQ + skey) * HEAD_DIM + sdseg;
    const size_t vg_base = ((size_t)bh * HEAD_DIM + svd) * SEQ + svseg;

    const int b  = bh >> 4;
    const int hh = bh & 15;

    #pragma unroll 1
    for (int pass = 0; pass < 2; ++pass) {
        const int qb   = pass ? (15 - pb) : pb;
        const int q0   = qb * 128 + wv * 32;     // wave's first q row
        const int diag = qb * 4 + wv;            // wave's diagonal tile index
        const int nt   = (qb + 1) * 4;           // tiles this block stages

        // ---- Q B-frags (hi/lo), 4 k-steps of 16 d. Pre-roped, pre-scaled. ----
        const size_t qrow_base = ((size_t)bh * SEQ + q0 + lq) * HEAD_DIM;
        bf16x8 qfh[4], qfl[4];
        #pragma unroll
        for (int kt = 0; kt < 4; ++kt) {
            qfh[kt] = *(const bf16x8*)&Qh_g[qrow_base + kt * 16 + hi5 * 8];
            qfl[kt] = *(const bf16x8*)&Ql_g[qrow_base + kt * 16 + hi5 * 8];
        }

        f32x16 oacc0, oacc1;
        #pragma unroll
        for (int r = 0; r < 16; ++r) { oacc0[r] = 0.f; oacc1[r] = 0.f; }
        float m_st = -INFINITY;   // running max for q = lq
        float l_st = 0.f;         // running denom for q = lq

        // prologue: stage tile 0 into buffer 0
        {
            uint4 kh = *(const uint4*)&Kh_g[kg_base];
            uint4 kl = *(const uint4*)&Kl_g[kg_base];
            uint4 vh = *(const uint4*)&Vh_g[vg_base];
            uint4 vl = *(const uint4*)&Vl_g[vg_base];
            *(uint4*)&sKh[0][skey * KSTR + sdseg] = kh;
            *(uint4*)&sKl[0][skey * KSTR + sdseg] = kl;
            *(uint4*)&sVh[0][svd * VSTR + svseg]  = vh;
            *(uint4*)&sVl[0][svd * VSTR + svseg]  = vl;
        }
        __syncthreads();

        uint4 r_kh, r_kl, r_vh, r_vl;
        for (int t = 0; t < nt; ++t) {
            const int cur = t & 1;
            // issue next tile's loads early (land during compute)
            if (t + 1 < nt) {
                const size_t koff = (size_t)(t + 1) * 32 * HEAD_DIM;
                const size_t voff = (size_t)(t + 1) * 32;
                r_kh = *(const uint4*)&Kh_g[kg_base + koff];
                r_kl = *(const uint4*)&Kl_g[kg_base + koff];
                r_vh = *(const uint4*)&Vh_g[vg_base + voff];
                r_vl = *(const uint4*)&Vl_g[vg_base + voff];
            }

            if (t <= diag) {   // wave-uniform: skip fully-masked tiles
                // ---- QK^T: S^T[key][q] = sum_d K[key][d] Q[q][d] ----
                f32x16 S;
                #pragma unroll
                for (int r = 0; r < 16; ++r) S[r] = 0.f;
                __builtin_amdgcn_s_setprio(1);
                #pragma unroll
                for (int kt = 0; kt < 4; ++kt) {
                    const int ko = (lane & 31) * KSTR + kt * 16 + hi5 * 8;
                    bf16x8 kh = *(const bf16x8*)&sKh[cur][ko];
                    bf16x8 kl = *(const bf16x8*)&sKl[cur][ko];
                    S = __builtin_amdgcn_mfma_f32_32x32x16_bf16(kh, qfh[kt], S, 0, 0, 0);
                    S = __builtin_amdgcn_mfma_f32_32x32x16_bf16(kh, qfl[kt], S, 0, 0, 0);
                    S = __builtin_amdgcn_mfma_f32_32x32x16_bf16(kl, qfh[kt], S, 0, 0, 0);
                }
                __builtin_amdgcn_s_setprio(0);

                // causal mask on the diagonal tile: key_local > q_local -> -inf
                if (t == diag) {
                    #pragma unroll
                    for (int r = 0; r < 16; ++r) {
                        const int keyl = (r & 3) + 8 * (r >> 2) + 4 * hi5;
                        if (keyl > lq) S[r] = -INFINITY;
                    }
                }

                // ---- online softmax (q = lq; row split across lane, lane^32) --
                float pmax = S[0];
                #pragma unroll
                for (int r = 1; r < 16; ++r) pmax = fmaxf(pmax, S[r]);
                pmax = fmaxf(pmax, __shfl_xor(pmax, 32));

                if (__any(pmax > m_st + 8.0f)) {       // rescale path (rare)
                    const float mnew = fmaxf(m_st, pmax);
                    const float corr = __expf(m_st - mnew);   // 0 on first tile
                    m_st = mnew;
                    l_st *= corr;
                    #pragma unroll
                    for (int r = 0; r < 16; ++r) {
                        const int qrow = (r & 3) + 8 * (r >> 2) + 4 * hi5;
                        const float c_o = __shfl(corr, qrow);  // corr of that q-row
                        oacc0[r] *= c_o;
                        oacc1[r] *= c_o;
                    }
                }

                float psum = 0.f;
                #pragma unroll
                for (int r = 0; r < 16; ++r) {
                    S[r] = __expf(S[r] - m_st);
                    psum += S[r];
                }
                psum += __shfl_xor(psum, 32);
                l_st += psum;

                // ---- P -> A-frags (hi/lo) via cvt_pk + shfl_xor(32) ----
                #pragma unroll
                for (int h = 0; h < 2; ++h) {          // 16-key halves
                    const int r0 = h * 8;
                    unsigned int Xh[4], Xl[4];
                    #pragma unroll
                    for (int c = 0; c < 4; ++c) {
                        const float p0 = S[r0 + 2*c], p1 = S[r0 + 2*c + 1];
                        Xh[c] = cvt_pk_bf16(p0, p1);
                        const float l0 = p0 - __uint_as_float(Xh[c] << 16);
                        const float l1 = p1 - __uint_as_float(Xh[c] & 0xFFFF0000u);
                        Xl[c] = cvt_pk_bf16(l0, l1);
                    }
                    unsigned int Yh[4], Yl[4];
                    #pragma unroll
                    for (int c = 0; c < 4; ++c) {
                        Yh[c] = (unsigned int)__shfl_xor((int)Xh[c], 32);
                        Yl[c] = (unsigned int)__shfl_xor((int)Xl[c], 32);
                    }
                    union { unsigned int u[4]; bf16x8 v; } pah, pal;
                    pah.u[0] = lo32 ? Xh[0] : Yh[2];
                    pah.u[1] = lo32 ? Xh[1] : Yh[3];
                    pah.u[2] = lo32 ? Yh[0] : Xh[2];
                    pah.u[3] = lo32 ? Yh[1] : Xh[3];
                    pal.u[0] = lo32 ? Xl[0] : Yl[2];
                    pal.u[1] = lo32 ? Xl[1] : Yl[3];
                    pal.u[2] = lo32 ? Yl[0] : Xl[2];
                    pal.u[3] = lo32 ? Yl[1] : Xl[3];

                    // ---- PV: O[q][d] += P[q][keys] V[keys][d] ----
                    const int vo0 = (0 * 32 + (lane & 31)) * VSTR + h * 16 + hi5 * 8;
                    const int vo1 = (1 * 32 + (lane & 31)) * VSTR + h * 16 + hi5 * 8;
                    bf16x8 vh0 = *(const bf16x8*)&sVh[cur][vo0];
                    bf16x8 vl0 = *(const bf16x8*)&sVl[cur][vo0];
                    bf16x8 vh1 = *(const bf16x8*)&sVh[cur][vo1];
                    bf16x8 vl1 = *(const bf16x8*)&sVl[cur][vo1];
                    __builtin_amdgcn_s_setprio(1);
                    oacc0 = __builtin_amdgcn_mfma_f32_32x32x16_bf16(pah.v, vh0, oacc0, 0, 0, 0);
                    oacc0 = __builtin_amdgcn_mfma_f32_32x32x16_bf16(pah.v, vl0, oacc0, 0, 0, 0);
                    oacc0 = __builtin_amdgcn_mfma_f32_32x32x16_bf16(pal.v, vh0, oacc0, 0, 0, 0);
                    oacc1 = __builtin_amdgcn_mfma_f32_32x32x16_bf16(pah.v, vh1, oacc1, 0, 0, 0);
                    oacc1 = __builtin_amdgcn_mfma_f32_32x32x16_bf16(pah.v, vl1, oacc1, 0, 0, 0);
                    oacc1 = __builtin_amdgcn_mfma_f32_32x32x16_bf16(pal.v, vh1, oacc1, 0, 0, 0);
                    __builtin_amdgcn_s_setprio(0);
                }
            }

            // stage next tile into the other buffer (prev tile's readers are
            // past the barrier at the end of the previous iteration)
            if (t + 1 < nt) {
                *(uint4*)&sKh[cur ^ 1][skey * KSTR + sdseg] = r_kh;
                *(uint4*)&sKl[cur ^ 1][skey * KSTR + sdseg] = r_kl;
                *(uint4*)&sVh[cur ^ 1][svd * VSTR + svseg]  = r_vh;
                *(uint4*)&sVl[cur ^ 1][svd * VSTR + svseg]  = r_vl;
            }
            __syncthreads();
        }

        // ---- epilogue: normalize, split hi/lo, store [b][s][h*64+d] ----
        const float linv = 1.0f / l_st;
        #pragma unroll
        for (int r = 0; r < 16; ++r) {
            const int qrow = (r & 3) + 8 * (r >> 2) + 4 * hi5;
            const float li = __shfl(linv, qrow);
            const int s = q0 + qrow;
            const size_t rowb = ((size_t)b * SEQ + s) * D_MODEL + hh * HEAD_DIM;
            const float v0 = oacc0[r] * li;
            const float v1 = oacc1[r] * li;
            const unsigned short h0 = f32_to_bf16_rne(v0);
            const unsigned short h1 = f32_to_bf16_rne(v1);
            attn_h[rowb + (lane & 31)]      = h0;
            attn_h[rowb + 32 + (lane & 31)] = h1;
            attn_l[rowb + (lane & 31)]      = f32_to_bf16_rne(v0 - bf16_to_f32(h0));
            attn_l[rowb + 32 + (lane & 31)] = f32_to_bf16_rne(v1 - bf16_to_f32(h1));
        }
    }
}

// ---------------------------------------------------------------------------
extern "C" void kernel_launch(void* const* d_in, const int* in_sizes, int n_in,
                              void* d_out, int out_size, void* d_ws, size_t ws_size,
                              hipStream_t stream) {
    const float* wq  = (const float*)d_in[0];
    const float* wk  = (const float*)d_in[1];
    const float* wv  = (const float*)d_in[2];
    const float* wo  = (const float*)d_in[3];
    const float* x   = (const float*)d_in[4];
    const int*   pos = (const int*)d_in[5];   // jax default: int32
    float* out = (float*)d_out;

    // workspace carve-up (~152 MiB)
    const size_t QKV_BYTES = (size_t)BATCH * NUM_HEADS * SEQ * HEAD_DIM * 2; // 16.78MB
    char* ws = (char*)d_ws;
    unsigned short* Qh  = (unsigned short*)ws; ws += QKV_BYTES;
    unsigned short* Ql  = (unsigned short*)ws; ws += QKV_BYTES;
    unsigned short* Kh  = (unsigned short*)ws; ws += QKV_BYTES;
    unsigned short* Kl  = (unsigned short*)ws; ws += QKV_BYTES;
    unsigned short* Vth = (unsigned short*)ws; ws += QKV_BYTES;
    unsigned short* Vtl = (unsigned short*)ws; ws += QKV_BYTES;
    unsigned short* xh  = (unsigned short*)ws; ws += QKV_BYTES;
    unsigned short* xl  = (unsigned short*)ws; ws += QKV_BYTES;
    unsigned short* wh  = (unsigned short*)ws; ws += (size_t)4 * 1024 * 1024 * 2;
    unsigned short* wl  = (unsigned short*)ws; ws += (size_t)4 * 1024 * 1024 * 2;
    float* cos_t = (float*)ws;                 ws += (size_t)SEQ * 32 * 4;
    float* sin_t = (float*)ws;                 ws += (size_t)SEQ * 32 * 4;
    // xh/xl dead after QKV GEMM -> reuse as attention output hi/lo
    unsigned short* attn_h = xh;
    unsigned short* attn_l = xl;

    rope_table_kernel<<<(SEQ * 32 + 255) / 256, 256, 0, stream>>>(pos, cos_t, sin_t);

    // pre-split inputs into hi/lo bf16
    split_kernel<<<(2097152 + 255) / 256, 256, 0, stream>>>(x, xh, xl, 2097152);
    split_kernel<<<(262144 + 255) / 256, 256, 0, stream>>>(wq, wh,           wl,           262144);
    split_kernel<<<(262144 + 255) / 256, 256, 0, stream>>>(wk, wh + 1048576, wl + 1048576, 262144);
    split_kernel<<<(262144 + 255) / 256, 256, 0, stream>>>(wv, wh + 2097152, wl + 2097152, 262144);
    split_kernel<<<(262144 + 255) / 256, 256, 0, stream>>>(wo, wh + 3145728, wl + 3145728, 262144);

    // QKV projection + RoPE + split + V-transpose (gload_lds split GEMM)
    mfma_split_gemm2<0><<<dim3(1536), 256, 0, stream>>>(
        xh, xl, wh, wl, cos_t, sin_t, Qh, Ql, Kh, Kl, Vth, Vtl, nullptr);

    // causal flash attention v3 (paired q-blocks + LDS dbuf)
    attn_mfma3_kernel<<<dim3(512), 256, 0, stream>>>(
        Qh, Ql, Kh, Kl, Vth, Vtl, attn_h, attn_l);

    // output projection (gload_lds split GEMM)
    mfma_split_gemm2<1><<<dim3(512), 256, 0, stream>>>(
        attn_h, attn_l, wh + 3145728, wl + 3145728, cos_t, sin_t,
        nullptr, nullptr, nullptr, nullptr, nullptr, nullptr, out);
}

// Round 9
// 444.297 us; speedup vs baseline: 8.9123x; 1.0801x over previous
//
#include <hip/hip_runtime.h>
#include <hip/hip_bf16.h>
#include <math.h>

// Problem constants (fixed by the reference)
#define D_MODEL   1024
#define NUM_HEADS 16
#define HEAD_DIM  64
#define BATCH     4
#define SEQ       2048
#define THETA     10000.0
#define M_TOTAL   (BATCH * SEQ)          // 8192 rows

typedef __attribute__((ext_vector_type(8)))  short bf16x8;   // 8 bf16 = 4 VGPR
typedef __attribute__((ext_vector_type(4)))  float f32x4;
typedef __attribute__((ext_vector_type(16))) float f32x16;

// ---------------------------------------------------------------------------
// fp32 <-> bf16 split helpers (RNE). a = hi + lo with |a - hi - lo| <= 2^-18|a|
// ---------------------------------------------------------------------------
__device__ __forceinline__ unsigned short f32_to_bf16_rne(float f) {
    unsigned int u = __float_as_uint(f);
    u += 0x7FFFu + ((u >> 16) & 1u);
    return (unsigned short)(u >> 16);
}
__device__ __forceinline__ float bf16_to_f32(unsigned short h) {
    return __uint_as_float(((unsigned int)h) << 16);
}
// packed pair: lo half = bf16(a), hi half = bf16(b)
__device__ __forceinline__ unsigned int cvt_pk_bf16(float a, float b) {
    unsigned int r;
    asm volatile("v_cvt_pk_bf16_f32 %0, %1, %2" : "=v"(r) : "v"(a), "v"(b));
    return r;
}

// ---------------------------------------------------------------------------
// RoPE cos/sin table: [SEQ][32] each, double-precision angle generation.
// ---------------------------------------------------------------------------
__global__ void rope_table_kernel(const int* __restrict__ pos,
                                  float* __restrict__ cos_t,
                                  float* __restrict__ sin_t) {
    int idx = blockIdx.x * blockDim.x + threadIdx.x;   // s*32 + i
    if (idx >= SEQ * 32) return;
    int s = idx >> 5;
    int i = idx & 31;
    double inv = pow((double)THETA, -((double)(2 * i)) / (double)HEAD_DIM);
    double ang = (double)pos[s] * inv;
    cos_t[idx] = (float)cos(ang);
    sin_t[idx] = (float)sin(ang);
}

// ---------------------------------------------------------------------------
// Split fp32 array -> hi/lo bf16 arrays (same layout). One float4 per thread.
// ---------------------------------------------------------------------------
__global__ void split_kernel(const float* __restrict__ src,
                             unsigned short* __restrict__ hi,
                             unsigned short* __restrict__ lo,
                             int n4) {
    int i = blockIdx.x * blockDim.x + threadIdx.x;
    if (i >= n4) return;
    float4 f = ((const float4*)src)[i];
    float fv[4] = {f.x, f.y, f.z, f.w};
    unsigned int hw[2], lw[2];
    #pragma unroll
    for (int j = 0; j < 2; ++j) {
        unsigned short h0 = f32_to_bf16_rne(fv[2*j]);
        unsigned short h1 = f32_to_bf16_rne(fv[2*j+1]);
        unsigned short l0 = f32_to_bf16_rne(fv[2*j]   - bf16_to_f32(h0));
        unsigned short l1 = f32_to_bf16_rne(fv[2*j+1] - bf16_to_f32(h1));
        hw[j] = (unsigned int)h0 | ((unsigned int)h1 << 16);
        lw[j] = (unsigned int)l0 | ((unsigned int)l1 << 16);
    }
    ((uint2*)hi)[i] = make_uint2(hw[0], hw[1]);
    ((uint2*)lo)[i] = make_uint2(lw[0], lw[1]);
}

// ---------------------------------------------------------------------------
// Split-precision MFMA GEMM v3 = R7-validated math/epilogue/swizzle + 2-phase
// counted-vmcnt pipeline (T3/T4 minimum form):
//   per K-step: vmcnt(8) [oldest batch landed] -> s_barrier -> ds_read frags
//   -> lgkmcnt(0)+sched_barrier -> s_barrier -> issue t+2 loads -> MFMA.
// Loads stay in flight across barriers (never drained to 0 mid-loop).
// LDS: [2 bufs][128][32] shorts per array = 64 KB total -> 2 blocks/CU.
// MODE 0: N-space = 3*1024 (Q|K|V); RoPE epilogue; V transposed [bh][64][S].
// MODE 1: plain fp32 write to Dout.
// ---------------------------------------------------------------------------
template<int MODE>
__global__ __launch_bounds__(256)
void mfma_split_gemm3(const unsigned short* __restrict__ Ah_g,   // [8192][1024]
                      const unsigned short* __restrict__ Al_g,
                      const unsigned short* __restrict__ Wh_g,   // [.][1024][1024]
                      const unsigned short* __restrict__ Wl_g,
                      const float* __restrict__ cos_t,
                      const float* __restrict__ sin_t,
                      unsigned short* __restrict__ Qh_g,
                      unsigned short* __restrict__ Ql_g,
                      unsigned short* __restrict__ Kh_g,
                      unsigned short* __restrict__ Kl_g,
                      unsigned short* __restrict__ Vh_g,
                      unsigned short* __restrict__ Vl_g,
                      float* __restrict__ Dout)
{
    __shared__ unsigned short sAh[2][128 * 32];
    __shared__ unsigned short sAl[2][128 * 32];
    __shared__ unsigned short sBh[2][128 * 32];
    __shared__ unsigned short sBl[2][128 * 32];

    const int tid  = threadIdx.x;
    const int lane = tid & 63;
    const int wvid = tid >> 6;

    // XCD-chunked decode (grid = 8 XCDs x (nblk x 8 mblk))
    const int bid = blockIdx.x;
    const int xcd = bid & 7;
    const int idx = bid >> 3;
    const int mblk = xcd * 8 + (idx & 7);
    const int nblk = idx >> 3;                  // MODE0: 0..23, MODE1: 0..7
    int proj = 0, nloc;
    if (MODE == 0) { proj = nblk >> 3; nloc = (nblk & 7) * 128; }
    else           { nloc = nblk * 128; }
    const int m0 = mblk * 128;

    const unsigned short* __restrict__ Wh = Wh_g + (size_t)proj * D_MODEL * D_MODEL;
    const unsigned short* __restrict__ Wl = Wl_g + (size_t)proj * D_MODEL * D_MODEL;

    // wave -> 64x64 output quadrant
    const int wr = (wvid >> 1) * 64;
    const int wc = (wvid & 1) * 64;

    // staging map: wave stages rows [wvid*32, wvid*32+32), 2 issues per array.
    // lane l -> dest (row r0+(l>>2), chunk l&3); src chunk = (l&3)^((l>>2)&3).
    const int r0 = wvid * 32;
    const int sr = lane >> 2;                              // 0..15
    const int sc = (((lane & 3) ^ (sr & 3)) << 3);         // swizzled src col
    const size_t a_src0 = (size_t)(m0 + r0 + sr) * D_MODEL + sc;
    const size_t a_src1 = a_src0 + (size_t)16 * D_MODEL;
    const size_t b_src0 = (size_t)(nloc + r0 + sr) * D_MODEL + sc;
    const size_t b_src1 = b_src0 + (size_t)16 * D_MODEL;

    // one 8-load batch = one K-tile of all four arrays
    auto STAGE = [&](int ktile, int bsel) {
        const int ko = ktile * 32;
        __builtin_amdgcn_global_load_lds((const void*)(Ah_g + a_src0 + ko),
                                         (void*)&sAh[bsel][r0 * 32],        16, 0, 0);
        __builtin_amdgcn_global_load_lds((const void*)(Ah_g + a_src1 + ko),
                                         (void*)&sAh[bsel][(r0 + 16) * 32], 16, 0, 0);
        __builtin_amdgcn_global_load_lds((const void*)(Al_g + a_src0 + ko),
                                         (void*)&sAl[bsel][r0 * 32],        16, 0, 0);
        __builtin_amdgcn_global_load_lds((const void*)(Al_g + a_src1 + ko),
                                         (void*)&sAl[bsel][(r0 + 16) * 32], 16, 0, 0);
        __builtin_amdgcn_global_load_lds((const void*)(Wh + b_src0 + ko),
                                         (void*)&sBh[bsel][r0 * 32],        16, 0, 0);
        __builtin_amdgcn_global_load_lds((const void*)(Wh + b_src1 + ko),
                                         (void*)&sBh[bsel][(r0 + 16) * 32], 16, 0, 0);
        __builtin_amdgcn_global_load_lds((const void*)(Wl + b_src0 + ko),
                                         (void*)&sBl[bsel][r0 * 32],        16, 0, 0);
        __builtin_amdgcn_global_load_lds((const void*)(Wl + b_src1 + ko),
                                         (void*)&sBl[bsel][(r0 + 16) * 32], 16, 0, 0);
    };

    f32x4 acc[4][4];
    #pragma unroll
    for (int i = 0; i < 4; ++i)
        #pragma unroll
        for (int j = 0; j < 4; ++j) {
            acc[i][j][0] = 0.f; acc[i][j][1] = 0.f;
            acc[i][j][2] = 0.f; acc[i][j][3] = 0.f;
        }

    // frag read map: row = (wr|wc) + i*16 + fr; 16B chunk = g ^ (fr&3)
    const int fr  = lane & 15;
    const int g   = lane >> 4;
    const int sw8 = ((g ^ (fr & 3)) << 3);                 // shorts

    const int NT = D_MODEL / 32;   // 32 K-tiles
    STAGE(0, 0);
    STAGE(1, 1);

    #pragma unroll 2
    for (int t = 0; t < NT; ++t) {
        const int cur = t & 1;
        // wait ONLY the oldest 8 loads (buf[cur]); buf[cur^1]'s stay in flight
        if (t + 1 < NT) asm volatile("s_waitcnt vmcnt(8)" ::: "memory");
        else            asm volatile("s_waitcnt vmcnt(0)" ::: "memory");
        __builtin_amdgcn_s_barrier();      // all waves: buf[cur] fully staged

        bf16x8 fah[4], fal[4], fbh[4], fbl[4];
        #pragma unroll
        for (int i = 0; i < 4; ++i) {
            fah[i] = *(const bf16x8*)&sAh[cur][(wr + i*16 + fr) * 32 + sw8];
            fal[i] = *(const bf16x8*)&sAl[cur][(wr + i*16 + fr) * 32 + sw8];
            fbh[i] = *(const bf16x8*)&sBh[cur][(wc + i*16 + fr) * 32 + sw8];
            fbl[i] = *(const bf16x8*)&sBl[cur][(wc + i*16 + fr) * 32 + sw8];
        }
        asm volatile("s_waitcnt lgkmcnt(0)" ::: "memory");  // frag reads done
        __builtin_amdgcn_sched_barrier(0);                  // pin reads here
        __builtin_amdgcn_s_barrier();      // all waves done reading buf[cur]

        if (t + 2 < NT) STAGE(t + 2, cur); // refill buf[cur]; lands over ~2 tiles

        __builtin_amdgcn_s_setprio(1);
        #pragma unroll
        for (int mi = 0; mi < 4; ++mi)
            #pragma unroll
            for (int ni = 0; ni < 4; ++ni) {
                acc[mi][ni] = __builtin_amdgcn_mfma_f32_16x16x32_bf16(fah[mi], fbh[ni], acc[mi][ni], 0, 0, 0);
                acc[mi][ni] = __builtin_amdgcn_mfma_f32_16x16x32_bf16(fah[mi], fbl[ni], acc[mi][ni], 0, 0, 0);
                acc[mi][ni] = __builtin_amdgcn_mfma_f32_16x16x32_bf16(fal[mi], fbh[ni], acc[mi][ni], 0, 0, 0);
            }
        __builtin_amdgcn_s_setprio(0);
    }

    // Epilogue (identical to validated R3/R7). C/D: col=lane&15, row=(lane>>4)*4+reg.
    const int fcol  = lane & 15;
    const int frow0 = (lane >> 4) * 4;
    #pragma unroll
    for (int mi = 0; mi < 4; ++mi) {
        const int m_base = m0 + wr + mi * 16 + frow0;
        #pragma unroll
        for (int ni = 0; ni < 4; ++ni) {
            const int n = nloc + wc + ni * 16 + fcol;
            if (MODE == 1) {
                #pragma unroll
                for (int r = 0; r < 4; ++r)
                    Dout[(size_t)(m_base + r) * D_MODEL + n] = acc[mi][ni][r];
            } else {
                const int h = n >> 6;
                const int d = n & 63;
                if (proj == 2) {
                    unsigned short vh[4], vl[4];
                    #pragma unroll
                    for (int r = 0; r < 4; ++r) {
                        float v = acc[mi][ni][r];
                        vh[r] = f32_to_bf16_rne(v);
                        vl[r] = f32_to_bf16_rne(v - bf16_to_f32(vh[r]));
                    }
                    const int b = m_base >> 11;
                    const int s = m_base & (SEQ - 1);
                    const size_t addr =
                        ((size_t)(b * NUM_HEADS + h) * HEAD_DIM + d) * SEQ + s;
                    *(uint2*)&Vh_g[addr] = make_uint2(
                        (unsigned)vh[0] | ((unsigned)vh[1] << 16),
                        (unsigned)vh[2] | ((unsigned)vh[3] << 16));
                    *(uint2*)&Vl_g[addr] = make_uint2(
                        (unsigned)vl[0] | ((unsigned)vl[1] << 16),
                        (unsigned)vl[2] | ((unsigned)vl[3] << 16));
                } else {
                    #pragma unroll
                    for (int r = 0; r < 4; ++r) {
                        const int m = m_base + r;
                        const int b = m >> 11;
                        const int s = m & (SEQ - 1);
                        float v = acc[mi][ni][r];
                        const float other = __shfl_xor(v, 1);
                        const float c  = cos_t[s * 32 + (d >> 1)];
                        const float sn = sin_t[s * 32 + (d >> 1)];
                        float res = (d & 1) ? fmaf(other, sn, v * c)
                                            : fmaf(-other, sn, v * c);
                        if (proj == 0) res *= 0.125f;   // fold 1/sqrt(64) into Q
                        unsigned short hi = f32_to_bf16_rne(res);
                        unsigned short lo = f32_to_bf16_rne(res - bf16_to_f32(hi));
                        const size_t addr =
                            ((size_t)(b * NUM_HEADS + h) * SEQ + s) * HEAD_DIM + d;
                        if (proj == 0) { Qh_g[addr] = hi; Ql_g[addr] = lo; }
                        else           { Kh_g[addr] = hi; Kl_g[addr] = lo; }
                    }
                }
            }
        }
    }
}

// ---------------------------------------------------------------------------
// Flash attention v3 (validated R6): paired q-blocks (uniform per-CU work),
// LDS double-buffer (one barrier/tile), setprio around MFMA clusters.
// ---------------------------------------------------------------------------
#define KSTR 72   // sK row stride in shorts (32 keys x 64 d + pad)
#define VSTR 40   // sV row stride in shorts (64 d x 32 keys + pad)

__global__ __launch_bounds__(256)
void attn_mfma3_kernel(const unsigned short* __restrict__ Qh_g,  // [bh][S][64]
                       const unsigned short* __restrict__ Ql_g,
                       const unsigned short* __restrict__ Kh_g,  // [bh][S][64]
                       const unsigned short* __restrict__ Kl_g,
                       const unsigned short* __restrict__ Vh_g,  // [bh][64][S]
                       const unsigned short* __restrict__ Vl_g,
                       unsigned short* __restrict__ attn_h,      // [B*S][1024]
                       unsigned short* __restrict__ attn_l)
{
    __shared__ unsigned short sKh[2][32 * KSTR];
    __shared__ unsigned short sKl[2][32 * KSTR];
    __shared__ unsigned short sVh[2][64 * VSTR];
    __shared__ unsigned short sVl[2][64 * VSTR];

    // grid: 512 = 64 bh x 8 pair-blocks. XCD-chunked: 8 bh per XCD.
    const int bid = blockIdx.x;
    const int swz = (bid & 7) * 64 + (bid >> 3);
    const int bh  = swz >> 3;        // 0..63
    const int pb  = swz & 7;         // pair id 0..7

    const int tid   = threadIdx.x;
    const int lane  = tid & 63;
    const int wv    = tid >> 6;          // wave 0..3
    const int lq    = lane & 31;         // q within wave tile (S^T col)
    const int hi5   = lane >> 5;         // 0/1
    const bool lo32 = (hi5 == 0);

    // ---- staging map (256 threads, one 32-key tile) ----
    const int skey = tid >> 3, sdseg = (tid & 7) * 8;       // K: [32 keys][64 d]
    const int svd  = tid >> 2, svseg = (tid & 3) * 8;       // V: [64 d][32 keys]
    const size_t kg_base = ((size_t)bh * SEQ + skey) * HEAD_DIM + sdseg;
    const size_t vg_base = ((size_t)bh * HEAD_DIM + svd) * SEQ + svseg;

    const int b  = bh >> 4;
    const int hh = bh & 15;

    #pragma unroll 1
    for (int pass = 0; pass < 2; ++pass) {
        const int qb   = pass ? (15 - pb) : pb;
        const int q0   = qb * 128 + wv * 32;     // wave's first q row
        const int diag = qb * 4 + wv;            // wave's diagonal tile index
        const int nt   = (qb + 1) * 4;           // tiles this block stages

        // ---- Q B-frags (hi/lo), 4 k-steps of 16 d. Pre-roped, pre-scaled. ----
        const size_t qrow_base = ((size_t)bh * SEQ + q0 + lq) * HEAD_DIM;
        bf16x8 qfh[4], qfl[4];
        #pragma unroll
        for (int kt = 0; kt < 4; ++kt) {
            qfh[kt] = *(const bf16x8*)&Qh_g[qrow_base + kt * 16 + hi5 * 8];
            qfl[kt] = *(const bf16x8*)&Ql_g[qrow_base + kt * 16 + hi5 * 8];
        }

        f32x16 oacc0, oacc1;
        #pragma unroll
        for (int r = 0; r < 16; ++r) { oacc0[r] = 0.f; oacc1[r] = 0.f; }
        float m_st = -INFINITY;   // running max for q = lq
        float l_st = 0.f;         // running denom for q = lq

        // prologue: stage tile 0 into buffer 0
        {
            uint4 kh = *(const uint4*)&Kh_g[kg_base];
            uint4 kl = *(const uint4*)&Kl_g[kg_base];
            uint4 vh = *(const uint4*)&Vh_g[vg_base];
            uint4 vl = *(const uint4*)&Vl_g[vg_base];
            *(uint4*)&sKh[0][skey * KSTR + sdseg] = kh;
            *(uint4*)&sKl[0][skey * KSTR + sdseg] = kl;
            *(uint4*)&sVh[0][svd * VSTR + svseg]  = vh;
            *(uint4*)&sVl[0][svd * VSTR + svseg]  = vl;
        }
        __syncthreads();

        uint4 r_kh, r_kl, r_vh, r_vl;
        for (int t = 0; t < nt; ++t) {
            const int cur = t & 1;
            // issue next tile's loads early (land during compute)
            if (t + 1 < nt) {
                const size_t koff = (size_t)(t + 1) * 32 * HEAD_DIM;
                const size_t voff = (size_t)(t + 1) * 32;
                r_kh = *(const uint4*)&Kh_g[kg_base + koff];
                r_kl = *(const uint4*)&Kl_g[kg_base + koff];
                r_vh = *(const uint4*)&Vh_g[vg_base + voff];
                r_vl = *(const uint4*)&Vl_g[vg_base + voff];
            }

            if (t <= diag) {   // wave-uniform: skip fully-masked tiles
                // ---- QK^T: S^T[key][q] = sum_d K[key][d] Q[q][d] ----
                f32x16 S;
                #pragma unroll
                for (int r = 0; r < 16; ++r) S[r] = 0.f;
                __builtin_amdgcn_s_setprio(1);
                #pragma unroll
                for (int kt = 0; kt < 4; ++kt) {
                    const int ko = (lane & 31) * KSTR + kt * 16 + hi5 * 8;
                    bf16x8 kh = *(const bf16x8*)&sKh[cur][ko];
                    bf16x8 kl = *(const bf16x8*)&sKl[cur][ko];
                    S = __builtin_amdgcn_mfma_f32_32x32x16_bf16(kh, qfh[kt], S, 0, 0, 0);
                    S = __builtin_amdgcn_mfma_f32_32x32x16_bf16(kh, qfl[kt], S, 0, 0, 0);
                    S = __builtin_amdgcn_mfma_f32_32x32x16_bf16(kl, qfh[kt], S, 0, 0, 0);
                }
                __builtin_amdgcn_s_setprio(0);

                // causal mask on the diagonal tile: key_local > q_local -> -inf
                if (t == diag) {
                    #pragma unroll
                    for (int r = 0; r < 16; ++r) {
                        const int keyl = (r & 3) + 8 * (r >> 2) + 4 * hi5;
                        if (keyl > lq) S[r] = -INFINITY;
                    }
                }

                // ---- online softmax (q = lq; row split across lane, lane^32) --
                float pmax = S[0];
                #pragma unroll
                for (int r = 1; r < 16; ++r) pmax = fmaxf(pmax, S[r]);
                pmax = fmaxf(pmax, __shfl_xor(pmax, 32));

                if (__any(pmax > m_st + 8.0f)) {       // rescale path (rare)
                    const float mnew = fmaxf(m_st, pmax);
                    const float corr = __expf(m_st - mnew);   // 0 on first tile
                    m_st = mnew;
                    l_st *= corr;
                    #pragma unroll
                    for (int r = 0; r < 16; ++r) {
                        const int qrow = (r & 3) + 8 * (r >> 2) + 4 * hi5;
                        const float c_o = __shfl(corr, qrow);  // corr of that q-row
                        oacc0[r] *= c_o;
                        oacc1[r] *= c_o;
                    }
                }

                float psum = 0.f;
                #pragma unroll
                for (int r = 0; r < 16; ++r) {
                    S[r] = __expf(S[r] - m_st);
                    psum += S[r];
                }
                psum += __shfl_xor(psum, 32);
                l_st += psum;

                // ---- P -> A-frags (hi/lo) via cvt_pk + shfl_xor(32) ----
                #pragma unroll
                for (int h = 0; h < 2; ++h) {          // 16-key halves
                    const int r0 = h * 8;
                    unsigned int Xh[4], Xl[4];
                    #pragma unroll
                    for (int c = 0; c < 4; ++c) {
                        const float p0 = S[r0 + 2*c], p1 = S[r0 + 2*c + 1];
                        Xh[c] = cvt_pk_bf16(p0, p1);
                        const float l0 = p0 - __uint_as_float(Xh[c] << 16);
                        const float l1 = p1 - __uint_as_float(Xh[c] & 0xFFFF0000u);
                        Xl[c] = cvt_pk_bf16(l0, l1);
                    }
                    unsigned int Yh[4], Yl[4];
                    #pragma unroll
                    for (int c = 0; c < 4; ++c) {
                        Yh[c] = (unsigned int)__shfl_xor((int)Xh[c], 32);
                        Yl[c] = (unsigned int)__shfl_xor((int)Xl[c], 32);
                    }
                    union { unsigned int u[4]; bf16x8 v; } pah, pal;
                    pah.u[0] = lo32 ? Xh[0] : Yh[2];
                    pah.u[1] = lo32 ? Xh[1] : Yh[3];
                    pah.u[2] = lo32 ? Yh[0] : Xh[2];
                    pah.u[3] = lo32 ? Yh[1] : Xh[3];
                    pal.u[0] = lo32 ? Xl[0] : Yl[2];
                    pal.u[1] = lo32 ? Xl[1] : Yl[3];
                    pal.u[2] = lo32 ? Yl[0] : Xl[2];
                    pal.u[3] = lo32 ? Yl[1] : Xl[3];

                    // ---- PV: O[q][d] += P[q][keys] V[keys][d] ----
                    const int vo0 = (0 * 32 + (lane & 31)) * VSTR + h * 16 + hi5 * 8;
                    const int vo1 = (1 * 32 + (lane & 31)) * VSTR + h * 16 + hi5 * 8;
                    bf16x8 vh0 = *(const bf16x8*)&sVh[cur][vo0];
                    bf16x8 vl0 = *(const bf16x8*)&sVl[cur][vo0];
                    bf16x8 vh1 = *(const bf16x8*)&sVh[cur][vo1];
                    bf16x8 vl1 = *(const bf16x8*)&sVl[cur][vo1];
                    __builtin_amdgcn_s_setprio(1);
                    oacc0 = __builtin_amdgcn_mfma_f32_32x32x16_bf16(pah.v, vh0, oacc0, 0, 0, 0);
                    oacc0 = __builtin_amdgcn_mfma_f32_32x32x16_bf16(pah.v, vl0, oacc0, 0, 0, 0);
                    oacc0 = __builtin_amdgcn_mfma_f32_32x32x16_bf16(pal.v, vh0, oacc0, 0, 0, 0);
                    oacc1 = __builtin_amdgcn_mfma_f32_32x32x16_bf16(pah.v, vh1, oacc1, 0, 0, 0);
                    oacc1 = __builtin_amdgcn_mfma_f32_32x32x16_bf16(pah.v, vl1, oacc1, 0, 0, 0);
                    oacc1 = __builtin_amdgcn_mfma_f32_32x32x16_bf16(pal.v, vh1, oacc1, 0, 0, 0);
                    __builtin_amdgcn_s_setprio(0);
                }
            }

            // stage next tile into the other buffer (prev tile's readers are
            // past the barrier at the end of the previous iteration)
            if (t + 1 < nt) {
                *(uint4*)&sKh[cur ^ 1][skey * KSTR + sdseg] = r_kh;
                *(uint4*)&sKl[cur ^ 1][skey * KSTR + sdseg] = r_kl;
                *(uint4*)&sVh[cur ^ 1][svd * VSTR + svseg]  = r_vh;
                *(uint4*)&sVl[cur ^ 1][svd * VSTR + svseg]  = r_vl;
            }
            __syncthreads();
        }

        // ---- epilogue: normalize, split hi/lo, store [b][s][h*64+d] ----
        const float linv = 1.0f / l_st;
        #pragma unroll
        for (int r = 0; r < 16; ++r) {
            const int qrow = (r & 3) + 8 * (r >> 2) + 4 * hi5;
            const float li = __shfl(linv, qrow);
            const int s = q0 + qrow;
            const size_t rowb = ((size_t)b * SEQ + s) * D_MODEL + hh * HEAD_DIM;
            const float v0 = oacc0[r] * li;
            const float v1 = oacc1[r] * li;
            const unsigned short h0 = f32_to_bf16_rne(v0);
            const unsigned short h1 = f32_to_bf16_rne(v1);
            attn_h[rowb + (lane & 31)]      = h0;
            attn_h[rowb + 32 + (lane & 31)] = h1;
            attn_l[rowb + (lane & 31)]      = f32_to_bf16_rne(v0 - bf16_to_f32(h0));
            attn_l[rowb + 32 + (lane & 31)] = f32_to_bf16_rne(v1 - bf16_to_f32(h1));
        }
    }
}

// ---------------------------------------------------------------------------
extern "C" void kernel_launch(void* const* d_in, const int* in_sizes, int n_in,
                              void* d_out, int out_size, void* d_ws, size_t ws_size,
                              hipStream_t stream) {
    const float* wq  = (const float*)d_in[0];
    const float* wk  = (const float*)d_in[1];
    const float* wv  = (const float*)d_in[2];
    const float* wo  = (const float*)d_in[3];
    const float* x   = (const float*)d_in[4];
    const int*   pos = (const int*)d_in[5];   // jax default: int32
    float* out = (float*)d_out;

    // workspace carve-up (~152 MiB)
    const size_t QKV_BYTES = (size_t)BATCH * NUM_HEADS * SEQ * HEAD_DIM * 2; // 16.78MB
    char* ws = (char*)d_ws;
    unsigned short* Qh  = (unsigned short*)ws; ws += QKV_BYTES;
    unsigned short* Ql  = (unsigned short*)ws; ws += QKV_BYTES;
    unsigned short* Kh  = (unsigned short*)ws; ws += QKV_BYTES;
    unsigned short* Kl  = (unsigned short*)ws; ws += QKV_BYTES;
    unsigned short* Vth = (unsigned short*)ws; ws += QKV_BYTES;
    unsigned short* Vtl = (unsigned short*)ws; ws += QKV_BYTES;
    unsigned short* xh  = (unsigned short*)ws; ws += QKV_BYTES;
    unsigned short* xl  = (unsigned short*)ws; ws += QKV_BYTES;
    unsigned short* wh  = (unsigned short*)ws; ws += (size_t)4 * 1024 * 1024 * 2;
    unsigned short* wl  = (unsigned short*)ws; ws += (size_t)4 * 1024 * 1024 * 2;
    float* cos_t = (float*)ws;                 ws += (size_t)SEQ * 32 * 4;
    float* sin_t = (float*)ws;                 ws += (size_t)SEQ * 32 * 4;
    // xh/xl dead after QKV GEMM -> reuse as attention output hi/lo
    unsigned short* attn_h = xh;
    unsigned short* attn_l = xl;

    rope_table_kernel<<<(SEQ * 32 + 255) / 256, 256, 0, stream>>>(pos, cos_t, sin_t);

    // pre-split inputs into hi/lo bf16
    split_kernel<<<(2097152 + 255) / 256, 256, 0, stream>>>(x, xh, xl, 2097152);
    split_kernel<<<(262144 + 255) / 256, 256, 0, stream>>>(wq, wh,           wl,           262144);
    split_kernel<<<(262144 + 255) / 256, 256, 0, stream>>>(wk, wh + 1048576, wl + 1048576, 262144);
    split_kernel<<<(262144 + 255) / 256, 256, 0, stream>>>(wv, wh + 2097152, wl + 2097152, 262144);
    split_kernel<<<(262144 + 255) / 256, 256, 0, stream>>>(wo, wh + 3145728, wl + 3145728, 262144);

    // QKV projection + RoPE + split + V-transpose (2-phase counted-vmcnt GEMM)
    mfma_split_gemm3<0><<<dim3(1536), 256, 0, stream>>>(
        xh, xl, wh, wl, cos_t, sin_t, Qh, Ql, Kh, Kl, Vth, Vtl, nullptr);

    // causal flash attention v3 (paired q-blocks + LDS dbuf)
    attn_mfma3_kernel<<<dim3(512), 256, 0, stream>>>(
        Qh, Ql, Kh, Kl, Vth, Vtl, attn_h, attn_l);

    // output projection (2-phase counted-vmcnt GEMM)
    mfma_split_gemm3<1><<<dim3(512), 256, 0, stream>>>(
        attn_h, attn_l, wh + 3145728, wl + 3145728, cos_t, sin_t,
        nullptr, nullptr, nullptr, nullptr, nullptr, nullptr, out);
}